// Round 7
// baseline (334.562 us; speedup 1.0000x reference)
//
#include <hip/hip_runtime.h>
#include <hip/hip_bf16.h>

typedef __hip_bfloat16 bf16_t;
typedef __attribute__((ext_vector_type(8))) short bf16x8;
typedef __attribute__((ext_vector_type(4))) float f32x4;

#define S_LEN   2048
#define D_MODEL 2048
#define N_QH    32
#define N_KVH   8
#define HEAD_D  64
#define KV_D    512
#define M_ROWS  4096
#define QK_SCALE (0.125f * 1.44269504088896340736f)   // att_scale * log2(e), folded into Q
#define NQT     16              // q-tiles of 128 rows

// ---------------- RoPE table (double precision, [2048][32] cos/sin) ----------------
__global__ void rope_table_kernel(float* __restrict__ cosT, float* __restrict__ sinT) {
    int pos = blockIdx.x * 2 + (threadIdx.x >> 5);
    int j   = threadIdx.x & 31;
    double invf = pow(10000.0, -(double)(2 * j) / 64.0);
    double a = (double)pos * invf;
    cosT[pos * 32 + j] = (float)cos(a);
    sinT[pos * 32 + j] = (float)sin(a);
}

// ---------------- weight transpose + convert: W[K][N] f32 -> Wt[N][K] bf16 ----------------
__global__ void wt_conv_kernel(const float* __restrict__ W, bf16_t* __restrict__ Wt,
                               int K, int N) {
    __shared__ float tile[32][33];
    int n0 = blockIdx.x * 32, k0 = blockIdx.y * 32;
    int tx = threadIdx.x & 31, ty = threadIdx.x >> 5;   // 32 x 8
#pragma unroll
    for (int i = 0; i < 4; i++) {
        int r = ty + i * 8;
        tile[r][tx] = W[(size_t)(k0 + r) * N + n0 + tx];
    }
    __syncthreads();
#pragma unroll
    for (int i = 0; i < 4; i++) {
        int r = ty + i * 8;
        Wt[(size_t)(n0 + r) * K + k0 + tx] = __float2bfloat16(tile[tx][r]);
    }
}

// ---------------- f32 -> bf16 elementwise (x4 vectorized) ----------------
struct __align__(8) bf16x4s { bf16_t x, y, z, w; };
__global__ void conv_bf16_kernel(const float* __restrict__ X, bf16_t* __restrict__ Y) {
    int i = blockIdx.x * 256 + threadIdx.x;
    float4 v = ((const float4*)X)[i];
    bf16x4s o;
    o.x = __float2bfloat16(v.x);
    o.y = __float2bfloat16(v.y);
    o.z = __float2bfloat16(v.z);
    o.w = __float2bfloat16(v.w);
    ((bf16x4s*)Y)[i] = o;
}

// ---------------- async 16B global->LDS ----------------
__device__ __forceinline__ void async_copy16(const bf16_t* g, bf16_t* l) {
    __builtin_amdgcn_global_load_lds((const __attribute__((address_space(1))) void*)g,
                                     (__attribute__((address_space(3))) void*)l, 16, 0, 0);
}

// ---------------- GEMM: C[M][N] = A[M][K] (bf16) * Bt[N][K]^T (bf16) + bias ----------------
// Block = BM x 64, 4 waves stacked in M (wave rows = BM/4, MI = BM/64 16-row frags).
// ROPE: rotary epilogue (bf16 out); QSCALE: multiply by QK_SCALE (Q proj only).
// OUTF32: fp32 out (final proj). VTOUT (BM=64): transposed out vt[(b*8+kvh)*64+d][s].
template <int BM, int ROPE, int OUTF32, int VTOUT, int QSCALE>
__global__ __launch_bounds__(256, 4)
void gqa_gemm_kernel(const bf16_t* __restrict__ A, const bf16_t* __restrict__ Bt,
                     const float* __restrict__ bias, void* __restrict__ Cout,
                     int M, int N, int K,
                     const float* __restrict__ cosT, const float* __restrict__ sinT) {
    constexpr int MI = BM / 64;
    __shared__ __align__(16) bf16_t As[BM * 32];
    __shared__ __align__(16) bf16_t Bs[64 * 32];
    __shared__ float VtE[VTOUT ? 64 * 65 : 1];   // [d=64][s=64+1 pad]

    const int t = threadIdx.x;
    const int am0 = blockIdx.y * BM;
    const int bn0 = blockIdx.x * 64;

    const int l = t & 63, w = t >> 6;
    const int lr = l & 15, lk = l >> 4;

    f32x4 acc[MI][4];
#pragma unroll
    for (int i = 0; i < MI; i++)
#pragma unroll
        for (int j = 0; j < 4; j++) acc[i][j] = (f32x4)0.0f;

    const int srow = t >> 2;            // 0..63
    const int scol = (t & 3) * 8;
    const bf16_t* aptr = A + (size_t)(am0 + srow) * K + scol;
    const bf16_t* bptr = Bt + (size_t)(bn0 + srow) * K + scol;
    bf16_t* aLds = As + t * 8;
    bf16_t* bLds = Bs + t * 8;

    for (int k0 = 0; k0 < K; k0 += 32) {
#pragma unroll
        for (int rb = 0; rb < MI; ++rb)
            async_copy16(aptr + (size_t)(rb * 64) * K + k0, aLds + rb * 2048);
        async_copy16(bptr + k0, bLds);
        __syncthreads();

        bf16x8 af[MI], bfr[4];
#pragma unroll
        for (int mi = 0; mi < MI; mi++)
            af[mi] = *(const bf16x8*)&As[(w * (MI * 16) + mi * 16 + lr) * 32 + lk * 8];
#pragma unroll
        for (int ni = 0; ni < 4; ni++)
            bfr[ni] = *(const bf16x8*)&Bs[(ni * 16 + lr) * 32 + lk * 8];
#pragma unroll
        for (int mi = 0; mi < MI; mi++)
#pragma unroll
            for (int ni = 0; ni < 4; ni++)
                acc[mi][ni] = __builtin_amdgcn_mfma_f32_16x16x32_bf16(af[mi], bfr[ni],
                                                                      acc[mi][ni], 0, 0, 0);
        __syncthreads();
    }

    // Epilogue. C/D layout: col = lane&15, row = (lane>>4)*4 + reg
    if (VTOUT) {
        // VtE[d][s]: d = ni*16+lr (col within 64), s = w*16 + lk*4 + reg (row within 64)
#pragma unroll
        for (int reg = 0; reg < 4; reg++)
#pragma unroll
            for (int ni = 0; ni < 4; ni++)
                VtE[(ni * 16 + lr) * 65 + w * 16 + lk * 4 + reg] =
                    acc[0][ni][reg] + bias[bn0 + ni * 16 + lr];
        __syncthreads();
        const int d = t & 63, w2 = t >> 6;
        const int bI = am0 >> 11;
        const int kvhI = bn0 >> 6;
        const int s0 = (am0 & (S_LEN - 1)) + w2 * 16;
        bf16_t* dst = (bf16_t*)Cout + ((size_t)(bI * N_KVH + kvhI) * HEAD_D + d) * S_LEN + s0;
        const float* src = &VtE[d * 65 + w2 * 16];
#pragma unroll
        for (int c = 0; c < 2; c++) {
            union { bf16x8 v; bf16_t e[8]; } u;
#pragma unroll
            for (int j = 0; j < 8; j++) u.e[j] = __float2bfloat16(src[c * 8 + j]);
            *(bf16x8*)(dst + c * 8) = u.v;
        }
        return;
    }
#pragma unroll
    for (int mi = 0; mi < MI; mi++) {
#pragma unroll
        for (int reg = 0; reg < 4; reg++) {
            int row = am0 + w * (MI * 16) + mi * 16 + lk * 4 + reg;
            if (OUTF32) {
                float* out = (float*)Cout;
#pragma unroll
                for (int ni = 0; ni < 4; ni++) {
                    int col = bn0 + ni * 16 + lr;
                    out[(size_t)row * N + col] = acc[mi][ni][reg] + bias[col];
                }
            } else if (ROPE) {
                bf16_t* out = (bf16_t*)Cout;
                int pos = row & (S_LEN - 1);
#pragma unroll
                for (int np = 0; np < 2; np++) {
                    int j = np * 16 + lr;              // d % 32 (head-local)
                    float cs = cosT[pos * 32 + j];
                    float sn = sinT[pos * 32 + j];
                    int col1 = bn0 + np * 16 + lr;
                    float x1 = acc[mi][np][reg] + bias[col1];
                    float x2 = acc[mi][np + 2][reg] + bias[col1 + 32];
                    float o1 = x1 * cs - x2 * sn;
                    float o2 = x2 * cs + x1 * sn;
                    if (QSCALE) { o1 *= QK_SCALE; o2 *= QK_SCALE; }
                    out[(size_t)row * N + col1]      = __float2bfloat16(o1);
                    out[(size_t)row * N + col1 + 32] = __float2bfloat16(o2);
                }
            } else {
                bf16_t* out = (bf16_t*)Cout;
#pragma unroll
                for (int ni = 0; ni < 4; ni++) {
                    int col = bn0 + ni * 16 + lr;
                    out[(size_t)row * N + col] =
                        __float2bfloat16(acc[mi][ni][reg] + bias[col]);
                }
            }
        }
    }
}

// ---------------- staging (512 threads: one 16B async copy per thread) ----------------
// LDS linear [64 key][64 d]; element (key, e) holds global d-chunk (e/8)^(key&7).
__device__ __forceinline__ void stage_K8(const bf16_t* KB, bf16_t* dst, int kt, int t) {
    const int skey = t >> 3;                // 0..63
    const int c    = (t & 7) ^ (skey & 7);  // source chunk
    async_copy16(KB + (size_t)(kt * 64 + skey) * KV_D + c * 8, dst + t * 8);
}
// LDS linear [64 d][64 key]; element (d, e) holds global key-chunk (e/8)^(d&7).
__device__ __forceinline__ void stage_V8(const bf16_t* VTb, bf16_t* dst, int kt, int t) {
    const int sd = t >> 3;                  // 0..63
    const int c  = (t & 7) ^ (sd & 7);      // source chunk
    async_copy16(VTb + (size_t)sd * S_LEN + kt * 64 + c * 8, dst + t * 8);
}

// ---------------- causal GQA flash attention (swapped-QK^T, 8 waves) ----------------
// grid (NQT/2, QH, B) = 512 uniform blocks, 512 threads (8 waves x 16 q-rows).
// Balanced pairing: block p does q-tiles p and NQT-1-p (34 K-tiles each).
// S^T = mfma(K,Q): lane owns ONE q-row; scale pre-folded into Q (log2 domain).
// Defer-max (T13): skip O-rescale when the whole wave's max grew <= 8.
__global__ __launch_bounds__(512, 4)
void gqa_attn_kernel(const bf16_t* __restrict__ Q, const bf16_t* __restrict__ Kb,
                     const bf16_t* __restrict__ VT, bf16_t* __restrict__ Ctx) {
    __shared__ __align__(16) bf16_t Ks[2][64 * 64];    // [key][d], source-swizzled
    __shared__ __align__(16) bf16_t Vs[2][64 * 64];    // [d][key], source-swizzled
    __shared__ __align__(16) bf16_t Pw[8][16 * 72];    // per-wave P [q][key]

    const int t = threadIdx.x, l = t & 63, w = t >> 6;   // w = 0..7
    const int lr = l & 15, lk = l >> 4;
    const int p  = blockIdx.x;
    const int h  = blockIdx.y;
    const int b  = blockIdx.z;
    const int kvh = h >> 2;

    const bf16_t* KB  = Kb + (size_t)b * S_LEN * KV_D + kvh * HEAD_D;
    const bf16_t* VTb = VT + ((size_t)(b * N_KVH + kvh) * HEAD_D) * S_LEN;

#pragma unroll
    for (int half = 0; half < 2; ++half) {
        const int qt  = half ? (NQT - 1 - p) : p;
        const int q0w = qt * 128 + w * 16;
        const int qg  = q0w + lr;                       // this lane's q row

        // Q fragments (A-layout: row=lane&15 -> q, k=(lane>>4)*8+i -> d)
        bf16x8 qf[2];
        {
            const bf16_t* qrow = Q + ((size_t)(b * S_LEN + qg)) * D_MODEL + h * HEAD_D;
            qf[0] = *(const bf16x8*)(qrow + lk * 8);
            qf[1] = *(const bf16x8*)(qrow + 32 + lk * 8);
        }

        float mrow = -1e30f, lrow = 0.f;
        f32x4 oaccT[4];                                 // O^T: d = df*16+lk*4+r, q = lr
#pragma unroll
        for (int df = 0; df < 4; df++) oaccT[df] = (f32x4)0.0f;

        const int nkt = 2 * qt + 2;

        stage_K8(KB, Ks[0], 0, t);
        stage_V8(VTb, Vs[0], 0, t);
        __syncthreads();

        int cur = 0;
        for (int kt = 0; kt < nkt; ++kt) {
            const bool pre = (kt + 1 < nkt);
            if (pre) {
                stage_K8(KB, Ks[cur ^ 1], kt + 1, t);
                stage_V8(VTb, Vs[cur ^ 1], kt + 1, t);
            }

            if (kt * 64 <= q0w + 15) {                  // wave-uniform causal skip
                const bool diag = (kt * 64 + 63 > q0w);

                // ---- S^T = mfma(K, Q): keys in rows, q in cols (pre-scaled) ----
                f32x4 sfrT[4];
#pragma unroll
                for (int ni = 0; ni < 4; ni++) sfrT[ni] = (f32x4)0.0f;
                __builtin_amdgcn_s_setprio(1);
#pragma unroll
                for (int ni = 0; ni < 4; ni++)
#pragma unroll
                    for (int ks = 0; ks < 2; ks++) {
                        bf16x8 kf = *(const bf16x8*)&Ks[cur][(ni * 16 + lr) * 64 +
                                        ((ks * 32 + lk * 8) ^ ((lr & 7) << 3))];
                        sfrT[ni] = __builtin_amdgcn_mfma_f32_16x16x32_bf16(kf, qf[ks],
                                                                           sfrT[ni], 0, 0, 0);
                    }
                __builtin_amdgcn_s_setprio(0);

                // ---- mask + in-register row max (already log2-scaled) ----
                float pv[16];
                float mx = -1e30f;
#pragma unroll
                for (int ni = 0; ni < 4; ni++)
#pragma unroll
                    for (int r = 0; r < 4; r++) {
                        float sc = sfrT[ni][r];
                        if (diag) {
                            int keyg = kt * 64 + ni * 16 + lk * 4 + r;
                            if (keyg > qg) sc = -1e30f;
                        }
                        pv[ni * 4 + r] = sc;
                        mx = fmaxf(mx, sc);
                    }
                mx = fmaxf(mx, __shfl_xor(mx, 16));
                mx = fmaxf(mx, __shfl_xor(mx, 32));

                // ---- defer-max: only rescale when some lane's max grew > 8 ----
                float mn = fmaxf(mrow, mx);
                if (!__all(mn - mrow <= 8.0f)) {
                    float csc = exp2f(mrow - mn);
                    lrow *= csc;
#pragma unroll
                    for (int df = 0; df < 4; df++) oaccT[df] *= csc;
                    mrow = mn;
                }

                float rsp[4] = {0.f, 0.f, 0.f, 0.f};
#pragma unroll
                for (int ni = 0; ni < 4; ni++)
#pragma unroll
                    for (int r = 0; r < 4; r++) {
                        float e = exp2f(pv[ni * 4 + r] - mrow);
                        pv[ni * 4 + r] = e;
                        rsp[ni] += e;
                    }
                float rs = (rsp[0] + rsp[1]) + (rsp[2] + rsp[3]);
                rs += __shfl_xor(rs, 16);
                rs += __shfl_xor(rs, 32);
                lrow += rs;

                // ---- P^T -> per-wave LDS as P[q][key]; 4 consecutive keys -> b64 ----
#pragma unroll
                for (int ni = 0; ni < 4; ni++) {
                    bf16x4s pk;
                    pk.x = __float2bfloat16(pv[ni * 4 + 0]);
                    pk.y = __float2bfloat16(pv[ni * 4 + 1]);
                    pk.z = __float2bfloat16(pv[ni * 4 + 2]);
                    pk.w = __float2bfloat16(pv[ni * 4 + 3]);
                    *(bf16x4s*)&Pw[w][lr * 72 + ni * 16 + lk * 4] = pk;
                }

                // ---- O^T += mfma(V^T, P^T) ----
                __builtin_amdgcn_s_setprio(1);
#pragma unroll
                for (int ks = 0; ks < 2; ks++) {
                    bf16x8 pf = *(const bf16x8*)&Pw[w][lr * 72 + ks * 32 + lk * 8];
#pragma unroll
                    for (int df = 0; df < 4; df++) {
                        bf16x8 vf = *(const bf16x8*)&Vs[cur][(df * 16 + lr) * 64 +
                                        ((ks * 32 + lk * 8) ^ ((lr & 7) << 3))];
                        oaccT[df] = __builtin_amdgcn_mfma_f32_16x16x32_bf16(vf, pf,
                                            oaccT[df], 0, 0, 0);
                    }
                }
                __builtin_amdgcn_s_setprio(0);
            }

            __syncthreads();
            cur ^= 1;
        }

        // ---- normalize + write ctx (lane owns q = qg; d = df*16+lk*4+0..3) ----
        {
            float inv = 1.0f / lrow;
            bf16_t* crow = Ctx + ((size_t)(b * S_LEN + qg)) * D_MODEL + h * HEAD_D;
#pragma unroll
            for (int df = 0; df < 4; df++) {
                bf16x4s ov;
                ov.x = __float2bfloat16(oaccT[df][0] * inv);
                ov.y = __float2bfloat16(oaccT[df][1] * inv);
                ov.z = __float2bfloat16(oaccT[df][2] * inv);
                ov.w = __float2bfloat16(oaccT[df][3] * inv);
                *(bf16x4s*)(crow + df * 16 + lk * 4) = ov;
            }
        }
    }
}

extern "C" void kernel_launch(void* const* d_in, const int* in_sizes, int n_in,
                              void* d_out, int out_size, void* d_ws, size_t ws_size,
                              hipStream_t stream) {
    const float* query = (const float*)d_in[0];
    const float* key_  = (const float*)d_in[1];
    const float* value = (const float*)d_in[2];
    const float* w_q = (const float*)d_in[3];
    const float* b_q = (const float*)d_in[4];
    const float* w_k = (const float*)d_in[5];
    const float* b_k = (const float*)d_in[6];
    const float* w_v = (const float*)d_in[7];
    const float* b_v = (const float*)d_in[8];
    const float* w_o = (const float*)d_in[9];
    const float* b_o = (const float*)d_in[10];
    float* out = (float*)d_out;

    char* ws = (char*)d_ws;
    bf16_t* Abuf = (bf16_t*)(ws);                       // 16MB (A staging, reused as ctx)
    bf16_t* qb   = (bf16_t*)(ws + (size_t)(16 << 20));  // 16MB
    bf16_t* kb   = (bf16_t*)(ws + (size_t)(32 << 20));  // 4MB
    bf16_t* vt   = (bf16_t*)(ws + (size_t)(36 << 20));  // 4MB (transposed V)
    bf16_t* wtq  = (bf16_t*)(ws + (size_t)(40 << 20));  // 8MB
    bf16_t* wtk  = (bf16_t*)(ws + (size_t)(48 << 20));  // 2MB
    bf16_t* wtv  = (bf16_t*)(ws + (size_t)(50 << 20));  // 2MB
    bf16_t* wto  = (bf16_t*)(ws + (size_t)(52 << 20));  // 8MB
    float* cosT  = (float*)(ws + (size_t)(60 << 20));   // 256KB
    float* sinT  = (float*)(ws + (size_t)(60 << 20) + (256 << 10));

    rope_table_kernel<<<S_LEN / 2, 64, 0, stream>>>(cosT, sinT);

    wt_conv_kernel<<<dim3(D_MODEL / 32, D_MODEL / 32), 256, 0, stream>>>(w_q, wtq, D_MODEL, D_MODEL);
    wt_conv_kernel<<<dim3(KV_D / 32, D_MODEL / 32), 256, 0, stream>>>(w_k, wtk, D_MODEL, KV_D);
    wt_conv_kernel<<<dim3(KV_D / 32, D_MODEL / 32), 256, 0, stream>>>(w_v, wtv, D_MODEL, KV_D);
    wt_conv_kernel<<<dim3(D_MODEL / 32, D_MODEL / 32), 256, 0, stream>>>(w_o, wto, D_MODEL, D_MODEL);

    const int n4blocks = (M_ROWS * D_MODEL / 4) / 256;

    // Q projection (+RoPE, pre-scaled by QK_SCALE): 1024 blocks, 4/CU
    conv_bf16_kernel<<<n4blocks, 256, 0, stream>>>(query, Abuf);
    gqa_gemm_kernel<128, 1, 0, 0, 1><<<dim3(D_MODEL / 64, M_ROWS / 128), 256, 0, stream>>>(
        Abuf, wtq, b_q, qb, M_ROWS, D_MODEL, D_MODEL, cosT, sinT);
    // K projection (+RoPE): BM=64 -> 512 blocks, 2/CU
    conv_bf16_kernel<<<n4blocks, 256, 0, stream>>>(key_, Abuf);
    gqa_gemm_kernel<64, 1, 0, 0, 0><<<dim3(KV_D / 64, M_ROWS / 64), 256, 0, stream>>>(
        Abuf, wtk, b_k, kb, M_ROWS, KV_D, D_MODEL, cosT, sinT);
    // V projection -> TRANSPOSED vt[(b*8+kvh)*64+d][s]: BM=64 -> 512 blocks
    conv_bf16_kernel<<<n4blocks, 256, 0, stream>>>(value, Abuf);
    gqa_gemm_kernel<64, 0, 0, 1, 0><<<dim3(KV_D / 64, M_ROWS / 64), 256, 0, stream>>>(
        Abuf, wtv, b_v, vt, M_ROWS, KV_D, D_MODEL, cosT, sinT);

    // Attention -> ctx (reuses Abuf); balanced pairing, 8-wave blocks
    gqa_attn_kernel<<<dim3(NQT / 2, N_QH, 2), 512, 0, stream>>>(qb, kb, vt, Abuf);

    // Output projection -> fp32 d_out: 1024 blocks, 4/CU
    gqa_gemm_kernel<128, 0, 1, 0, 0><<<dim3(D_MODEL / 64, M_ROWS / 128), 256, 0, stream>>>(
        Abuf, wto, b_o, out, M_ROWS, D_MODEL, D_MODEL, cosT, sinT);
}

// Round 8
// 286.690 us; speedup vs baseline: 1.1670x; 1.1670x over previous
//
#include <hip/hip_runtime.h>
#include <hip/hip_bf16.h>

typedef __hip_bfloat16 bf16_t;
typedef __attribute__((ext_vector_type(8))) short bf16x8;
typedef __attribute__((ext_vector_type(4))) float f32x4;

#define S_LEN   2048
#define D_MODEL 2048
#define N_QH    32
#define N_KVH   8
#define HEAD_D  64
#define KV_D    512
#define M_ROWS  4096
#define QK_SCALE (0.125f * 1.44269504088896340736f)   // att_scale * log2(e), folded into Q
#define NQT     16              // q-tiles of 128 rows

// ---------------- RoPE table (double precision, [2048][32] cos/sin) ----------------
__global__ void rope_table_kernel(float* __restrict__ cosT, float* __restrict__ sinT) {
    int pos = blockIdx.x * 2 + (threadIdx.x >> 5);
    int j   = threadIdx.x & 31;
    double invf = pow(10000.0, -(double)(2 * j) / 64.0);
    double a = (double)pos * invf;
    cosT[pos * 32 + j] = (float)cos(a);
    sinT[pos * 32 + j] = (float)sin(a);
}

// ---------------- weight transpose + convert: W[K][N] f32 -> Wt[N][K] bf16 ----------------
__global__ void wt_conv_kernel(const float* __restrict__ W, bf16_t* __restrict__ Wt,
                               int K, int N) {
    __shared__ float tile[32][33];
    int n0 = blockIdx.x * 32, k0 = blockIdx.y * 32;
    int tx = threadIdx.x & 31, ty = threadIdx.x >> 5;   // 32 x 8
#pragma unroll
    for (int i = 0; i < 4; i++) {
        int r = ty + i * 8;
        tile[r][tx] = W[(size_t)(k0 + r) * N + n0 + tx];
    }
    __syncthreads();
#pragma unroll
    for (int i = 0; i < 4; i++) {
        int r = ty + i * 8;
        Wt[(size_t)(n0 + r) * K + k0 + tx] = __float2bfloat16(tile[tx][r]);
    }
}

// ---------------- f32 -> bf16 elementwise (x4 vectorized) ----------------
struct __align__(8) bf16x4s { bf16_t x, y, z, w; };
__global__ void conv_bf16_kernel(const float* __restrict__ X, bf16_t* __restrict__ Y) {
    int i = blockIdx.x * 256 + threadIdx.x;
    float4 v = ((const float4*)X)[i];
    bf16x4s o;
    o.x = __float2bfloat16(v.x);
    o.y = __float2bfloat16(v.y);
    o.z = __float2bfloat16(v.z);
    o.w = __float2bfloat16(v.w);
    ((bf16x4s*)Y)[i] = o;
}

// ---------------- async 16B global->LDS ----------------
__device__ __forceinline__ void async_copy16(const bf16_t* g, bf16_t* l) {
    __builtin_amdgcn_global_load_lds((const __attribute__((address_space(1))) void*)g,
                                     (__attribute__((address_space(3))) void*)l, 16, 0, 0);
}

// ---------------- GEMM: C[M][N] = A[M][K] (bf16) * Bt[N][K]^T (bf16) + bias ----------------
// Round-5 verified structure: 128x128 tile, 2x2 wave grid, 64x64 per wave.
// ROPE: rotary epilogue (bf16 out); QSCALE: multiply by QK_SCALE (Q proj only).
// OUTF32: fp32 out (final projection).
template <int ROPE, int OUTF32, int QSCALE>
__global__ __launch_bounds__(256, 2)
void gqa_gemm_kernel(const bf16_t* __restrict__ A, const bf16_t* __restrict__ Bt,
                     const float* __restrict__ bias, void* __restrict__ Cout,
                     int M, int N, int K,
                     const float* __restrict__ cosT, const float* __restrict__ sinT) {
    __shared__ __align__(16) bf16_t As[128 * 32];
    __shared__ __align__(16) bf16_t Bs[128 * 32];

    const int t = threadIdx.x;
    const int am0 = blockIdx.y * 128;
    const int bn0 = blockIdx.x * 128;

    const int l = t & 63, w = t >> 6;
    const int wr = w >> 1, wc = w & 1;
    const int lr = l & 15, lk = l >> 4;

    f32x4 acc[4][4];
#pragma unroll
    for (int i = 0; i < 4; i++)
#pragma unroll
        for (int j = 0; j < 4; j++) acc[i][j] = (f32x4)0.0f;

    const int srow = t >> 2;            // 0..63
    const int scol = (t & 3) * 8;
    const bf16_t* aptr = A + (size_t)(am0 + srow) * K + scol;
    const bf16_t* bptr = Bt + (size_t)(bn0 + srow) * K + scol;
    bf16_t* aLds = As + t * 8;
    bf16_t* bLds = Bs + t * 8;

    for (int k0 = 0; k0 < K; k0 += 32) {
        async_copy16(aptr + k0,                  aLds);
        async_copy16(aptr + (size_t)64 * K + k0, aLds + 2048);
        async_copy16(bptr + k0,                  bLds);
        async_copy16(bptr + (size_t)64 * K + k0, bLds + 2048);
        __syncthreads();

        bf16x8 af[4], bfr[4];
#pragma unroll
        for (int mi = 0; mi < 4; mi++)
            af[mi] = *(const bf16x8*)&As[(wr * 64 + mi * 16 + lr) * 32 + lk * 8];
#pragma unroll
        for (int ni = 0; ni < 4; ni++)
            bfr[ni] = *(const bf16x8*)&Bs[(wc * 64 + ni * 16 + lr) * 32 + lk * 8];
#pragma unroll
        for (int mi = 0; mi < 4; mi++)
#pragma unroll
            for (int ni = 0; ni < 4; ni++)
                acc[mi][ni] = __builtin_amdgcn_mfma_f32_16x16x32_bf16(af[mi], bfr[ni],
                                                                      acc[mi][ni], 0, 0, 0);
        __syncthreads();
    }

    // Epilogue. C/D layout: col = lane&15, row = (lane>>4)*4 + reg
#pragma unroll
    for (int mi = 0; mi < 4; mi++) {
#pragma unroll
        for (int reg = 0; reg < 4; reg++) {
            int row = am0 + wr * 64 + mi * 16 + lk * 4 + reg;
            if (OUTF32) {
                float* out = (float*)Cout;
#pragma unroll
                for (int ni = 0; ni < 4; ni++) {
                    int col = bn0 + wc * 64 + ni * 16 + lr;
                    out[(size_t)row * N + col] = acc[mi][ni][reg] + bias[col];
                }
            } else if (ROPE) {
                bf16_t* out = (bf16_t*)Cout;
                int pos = row & (S_LEN - 1);
#pragma unroll
                for (int np = 0; np < 2; np++) {
                    int j = np * 16 + lr;              // d % 32 (head-local)
                    float cs = cosT[pos * 32 + j];
                    float sn = sinT[pos * 32 + j];
                    int col1 = bn0 + wc * 64 + np * 16 + lr;
                    float x1 = acc[mi][np][reg] + bias[col1];
                    float x2 = acc[mi][np + 2][reg] + bias[col1 + 32];
                    float o1 = x1 * cs - x2 * sn;
                    float o2 = x2 * cs + x1 * sn;
                    if (QSCALE) { o1 *= QK_SCALE; o2 *= QK_SCALE; }
                    out[(size_t)row * N + col1]      = __float2bfloat16(o1);
                    out[(size_t)row * N + col1 + 32] = __float2bfloat16(o2);
                }
            } else {
                bf16_t* out = (bf16_t*)Cout;
#pragma unroll
                for (int ni = 0; ni < 4; ni++) {
                    int col = bn0 + wc * 64 + ni * 16 + lr;
                    out[(size_t)row * N + col] =
                        __float2bfloat16(acc[mi][ni][reg] + bias[col]);
                }
            }
        }
    }
}

// ---------------- fused K+V projection kernel ----------------
// grid (KV_D/64, M/128, 2): z=0 -> K proj (+RoPE) into kb[M][512];
// z=1 -> V proj, TRANSPOSED into vt[(b*8+kvh)*64+d][s]. Both halves run
// concurrently. A read as fp32 directly (reg-staged + inline convert);
// B (bf16 weights) via global_load_lds. 128x64 tile, 4 waves stacked in M.
__global__ __launch_bounds__(256, 2)
void gqa_kv_kernel(const float* __restrict__ Key, const float* __restrict__ Val,
                   const bf16_t* __restrict__ Wtk, const bf16_t* __restrict__ Wtv,
                   const float* __restrict__ bk, const float* __restrict__ bv,
                   bf16_t* __restrict__ Kout, bf16_t* __restrict__ VtOut,
                   const float* __restrict__ cosT, const float* __restrict__ sinT) {
    constexpr int K = D_MODEL;
    __shared__ __align__(16) bf16_t As[128 * 32];
    __shared__ __align__(16) bf16_t Bs[64 * 32];
    __shared__ float VtE[4 * 64 * 33];                 // per-wave [64 d][32 s +1]

    const int z = blockIdx.z;
    const float* A32  = z ? Val : Key;
    const bf16_t* Bt  = z ? Wtv : Wtk;
    const float* bias = z ? bv : bk;

    const int t = threadIdx.x;
    const int am0 = blockIdx.y * 128;
    const int bn0 = blockIdx.x * 64;
    const int l = t & 63, w = t >> 6;
    const int lr = l & 15, lk = l >> 4;

    f32x4 acc[2][4];
#pragma unroll
    for (int i = 0; i < 2; i++)
#pragma unroll
        for (int j = 0; j < 4; j++) acc[i][j] = (f32x4)0.0f;

    const int srow = t >> 2;            // 0..63
    const int scol = (t & 3) * 8;
    const float*  aptr = A32 + (size_t)(am0 + srow) * K + scol;
    const bf16_t* bptr = Bt + (size_t)(bn0 + srow) * K + scol;
    bf16_t* bLds = Bs + t * 8;

    for (int k0 = 0; k0 < K; k0 += 32) {
        async_copy16(bptr + k0, bLds);          // B: async direct-to-LDS
#pragma unroll
        for (int rb = 0; rb < 2; ++rb) {        // A: fp32 -> bf16 reg-staged
            const float* ap = aptr + (size_t)(rb * 64) * K + k0;
            float4 v0 = ((const float4*)ap)[0];
            float4 v1 = ((const float4*)ap)[1];
            union { bf16x8 v; bf16_t e[8]; } u;
            u.e[0] = __float2bfloat16(v0.x); u.e[1] = __float2bfloat16(v0.y);
            u.e[2] = __float2bfloat16(v0.z); u.e[3] = __float2bfloat16(v0.w);
            u.e[4] = __float2bfloat16(v1.x); u.e[5] = __float2bfloat16(v1.y);
            u.e[6] = __float2bfloat16(v1.z); u.e[7] = __float2bfloat16(v1.w);
            *(bf16x8*)&As[rb * 2048 + t * 8] = u.v;
        }
        __syncthreads();

        bf16x8 af[2], bfr[4];
#pragma unroll
        for (int mi = 0; mi < 2; mi++)
            af[mi] = *(const bf16x8*)&As[(w * 32 + mi * 16 + lr) * 32 + lk * 8];
#pragma unroll
        for (int ni = 0; ni < 4; ni++)
            bfr[ni] = *(const bf16x8*)&Bs[(ni * 16 + lr) * 32 + lk * 8];
#pragma unroll
        for (int mi = 0; mi < 2; mi++)
#pragma unroll
            for (int ni = 0; ni < 4; ni++)
                acc[mi][ni] = __builtin_amdgcn_mfma_f32_16x16x32_bf16(af[mi], bfr[ni],
                                                                      acc[mi][ni], 0, 0, 0);
        __syncthreads();
    }

    if (z == 0) {
        // K projection: RoPE epilogue, row-major kb[M][KV_D]
#pragma unroll
        for (int mi = 0; mi < 2; mi++)
#pragma unroll
            for (int reg = 0; reg < 4; reg++) {
                int row = am0 + w * 32 + mi * 16 + lk * 4 + reg;
                int pos = row & (S_LEN - 1);
#pragma unroll
                for (int np = 0; np < 2; np++) {
                    int j = np * 16 + lr;
                    float cs = cosT[pos * 32 + j];
                    float sn = sinT[pos * 32 + j];
                    int col1 = bn0 + np * 16 + lr;
                    float x1 = acc[mi][np][reg] + bias[col1];
                    float x2 = acc[mi][np + 2][reg] + bias[col1 + 32];
                    Kout[(size_t)row * KV_D + col1]      = __float2bfloat16(x1 * cs - x2 * sn);
                    Kout[(size_t)row * KV_D + col1 + 32] = __float2bfloat16(x2 * cs + x1 * sn);
                }
            }
    } else {
        // V projection: transpose via per-wave LDS tile [64 d][32 s +1 pad]
#pragma unroll
        for (int mi = 0; mi < 2; mi++)
#pragma unroll
            for (int reg = 0; reg < 4; reg++)
#pragma unroll
                for (int ni = 0; ni < 4; ni++)
                    VtE[(w * 64 + ni * 16 + lr) * 33 + mi * 16 + lk * 4 + reg] =
                        acc[mi][ni][reg] + bias[bn0 + ni * 16 + lr];
        __syncthreads();
        const int d = l;                       // 0..63
        const int bI = am0 >> 11;
        const int kvhI = bn0 >> 6;
        const int sl = (am0 & (S_LEN - 1)) + w * 32;
        bf16_t* dst = VtOut + ((size_t)(bI * N_KVH + kvhI) * HEAD_D + d) * S_LEN + sl;
        const float* src = &VtE[(w * 64 + d) * 33];
#pragma unroll
        for (int c = 0; c < 4; c++) {
            union { bf16x8 v; bf16_t e[8]; } u;
#pragma unroll
            for (int j = 0; j < 8; j++) u.e[j] = __float2bfloat16(src[c * 8 + j]);
            *(bf16x8*)(dst + c * 8) = u.v;
        }
    }
}

// ---------------- staging (512 threads: one 16B async copy per thread) ----------------
// LDS linear [64 key][64 d]; element (key, e) holds global d-chunk (e/8)^(key&7).
__device__ __forceinline__ void stage_K8(const bf16_t* KB, bf16_t* dst, int kt, int t) {
    const int skey = t >> 3;                // 0..63
    const int c    = (t & 7) ^ (skey & 7);  // source chunk
    async_copy16(KB + (size_t)(kt * 64 + skey) * KV_D + c * 8, dst + t * 8);
}
// LDS linear [64 d][64 key]; element (d, e) holds global key-chunk (e/8)^(d&7).
__device__ __forceinline__ void stage_V8(const bf16_t* VTb, bf16_t* dst, int kt, int t) {
    const int sd = t >> 3;                  // 0..63
    const int c  = (t & 7) ^ (sd & 7);      // source chunk
    async_copy16(VTb + (size_t)sd * S_LEN + kt * 64 + c * 8, dst + t * 8);
}

// ---------------- causal GQA flash attention (swapped-QK^T, 8 waves) ----------------
// grid (NQT/2, QH, B) = 512 uniform blocks, 512 threads (8 waves x 16 q-rows).
// Balanced pairing: block p does q-tiles p and NQT-1-p (34 K-tiles each).
// S^T = mfma(K,Q): lane owns ONE q-row; scale pre-folded into Q (log2 domain).
// Defer-max (T13): skip O-rescale when the whole wave's max grew <= 8.
__global__ __launch_bounds__(512, 4)
void gqa_attn_kernel(const bf16_t* __restrict__ Q, const bf16_t* __restrict__ Kb,
                     const bf16_t* __restrict__ VT, bf16_t* __restrict__ Ctx) {
    __shared__ __align__(16) bf16_t Ks[2][64 * 64];    // [key][d], source-swizzled
    __shared__ __align__(16) bf16_t Vs[2][64 * 64];    // [d][key], source-swizzled
    __shared__ __align__(16) bf16_t Pw[8][16 * 72];    // per-wave P [q][key]

    const int t = threadIdx.x, l = t & 63, w = t >> 6;   // w = 0..7
    const int lr = l & 15, lk = l >> 4;
    const int p  = blockIdx.x;
    const int h  = blockIdx.y;
    const int b  = blockIdx.z;
    const int kvh = h >> 2;

    const bf16_t* KB  = Kb + (size_t)b * S_LEN * KV_D + kvh * HEAD_D;
    const bf16_t* VTb = VT + ((size_t)(b * N_KVH + kvh) * HEAD_D) * S_LEN;

#pragma unroll
    for (int half = 0; half < 2; ++half) {
        const int qt  = half ? (NQT - 1 - p) : p;
        const int q0w = qt * 128 + w * 16;
        const int qg  = q0w + lr;                       // this lane's q row

        // Q fragments (A-layout: row=lane&15 -> q, k=(lane>>4)*8+i -> d)
        bf16x8 qf[2];
        {
            const bf16_t* qrow = Q + ((size_t)(b * S_LEN + qg)) * D_MODEL + h * HEAD_D;
            qf[0] = *(const bf16x8*)(qrow + lk * 8);
            qf[1] = *(const bf16x8*)(qrow + 32 + lk * 8);
        }

        float mrow = -1e30f, lrow = 0.f;
        f32x4 oaccT[4];                                 // O^T: d = df*16+lk*4+r, q = lr
#pragma unroll
        for (int df = 0; df < 4; df++) oaccT[df] = (f32x4)0.0f;

        const int nkt = 2 * qt + 2;

        stage_K8(KB, Ks[0], 0, t);
        stage_V8(VTb, Vs[0], 0, t);
        __syncthreads();

        int cur = 0;
        for (int kt = 0; kt < nkt; ++kt) {
            const bool pre = (kt + 1 < nkt);
            if (pre) {
                stage_K8(KB, Ks[cur ^ 1], kt + 1, t);
                stage_V8(VTb, Vs[cur ^ 1], kt + 1, t);
            }

            if (kt * 64 <= q0w + 15) {                  // wave-uniform causal skip
                const bool diag = (kt * 64 + 63 > q0w);

                // ---- S^T = mfma(K, Q): keys in rows, q in cols (pre-scaled) ----
                f32x4 sfrT[4];
#pragma unroll
                for (int ni = 0; ni < 4; ni++) sfrT[ni] = (f32x4)0.0f;
                __builtin_amdgcn_s_setprio(1);
#pragma unroll
                for (int ni = 0; ni < 4; ni++)
#pragma unroll
                    for (int ks = 0; ks < 2; ks++) {
                        bf16x8 kf = *(const bf16x8*)&Ks[cur][(ni * 16 + lr) * 64 +
                                        ((ks * 32 + lk * 8) ^ ((lr & 7) << 3))];
                        sfrT[ni] = __builtin_amdgcn_mfma_f32_16x16x32_bf16(kf, qf[ks],
                                                                           sfrT[ni], 0, 0, 0);
                    }
                __builtin_amdgcn_s_setprio(0);

                // ---- mask + in-register row max (already log2-scaled) ----
                float pv[16];
                float mx = -1e30f;
#pragma unroll
                for (int ni = 0; ni < 4; ni++)
#pragma unroll
                    for (int r = 0; r < 4; r++) {
                        float sc = sfrT[ni][r];
                        if (diag) {
                            int keyg = kt * 64 + ni * 16 + lk * 4 + r;
                            if (keyg > qg) sc = -1e30f;
                        }
                        pv[ni * 4 + r] = sc;
                        mx = fmaxf(mx, sc);
                    }
                mx = fmaxf(mx, __shfl_xor(mx, 16));
                mx = fmaxf(mx, __shfl_xor(mx, 32));

                // ---- defer-max: only rescale when some lane's max grew > 8 ----
                float mn = fmaxf(mrow, mx);
                if (!__all(mn - mrow <= 8.0f)) {
                    float csc = exp2f(mrow - mn);
                    lrow *= csc;
#pragma unroll
                    for (int df = 0; df < 4; df++) oaccT[df] *= csc;
                    mrow = mn;
                }

                float rsp[4] = {0.f, 0.f, 0.f, 0.f};
#pragma unroll
                for (int ni = 0; ni < 4; ni++)
#pragma unroll
                    for (int r = 0; r < 4; r++) {
                        float e = exp2f(pv[ni * 4 + r] - mrow);
                        pv[ni * 4 + r] = e;
                        rsp[ni] += e;
                    }
                float rs = (rsp[0] + rsp[1]) + (rsp[2] + rsp[3]);
                rs += __shfl_xor(rs, 16);
                rs += __shfl_xor(rs, 32);
                lrow += rs;

                // ---- P^T -> per-wave LDS as P[q][key]; 4 consecutive keys -> b64 ----
#pragma unroll
                for (int ni = 0; ni < 4; ni++) {
                    bf16x4s pk;
                    pk.x = __float2bfloat16(pv[ni * 4 + 0]);
                    pk.y = __float2bfloat16(pv[ni * 4 + 1]);
                    pk.z = __float2bfloat16(pv[ni * 4 + 2]);
                    pk.w = __float2bfloat16(pv[ni * 4 + 3]);
                    *(bf16x4s*)&Pw[w][lr * 72 + ni * 16 + lk * 4] = pk;
                }

                // ---- O^T += mfma(V^T, P^T) ----
                __builtin_amdgcn_s_setprio(1);
#pragma unroll
                for (int ks = 0; ks < 2; ks++) {
                    bf16x8 pf = *(const bf16x8*)&Pw[w][lr * 72 + ks * 32 + lk * 8];
#pragma unroll
                    for (int df = 0; df < 4; df++) {
                        bf16x8 vf = *(const bf16x8*)&Vs[cur][(df * 16 + lr) * 64 +
                                        ((ks * 32 + lk * 8) ^ ((lr & 7) << 3))];
                        oaccT[df] = __builtin_amdgcn_mfma_f32_16x16x32_bf16(vf, pf,
                                            oaccT[df], 0, 0, 0);
                    }
                }
                __builtin_amdgcn_s_setprio(0);
            }

            __syncthreads();
            cur ^= 1;
        }

        // ---- normalize + write ctx (lane owns q = qg; d = df*16+lk*4+0..3) ----
        {
            float inv = 1.0f / lrow;
            bf16_t* crow = Ctx + ((size_t)(b * S_LEN + qg)) * D_MODEL + h * HEAD_D;
#pragma unroll
            for (int df = 0; df < 4; df++) {
                bf16x4s ov;
                ov.x = __float2bfloat16(oaccT[df][0] * inv);
                ov.y = __float2bfloat16(oaccT[df][1] * inv);
                ov.z = __float2bfloat16(oaccT[df][2] * inv);
                ov.w = __float2bfloat16(oaccT[df][3] * inv);
                *(bf16x4s*)(crow + df * 16 + lk * 4) = ov;
            }
        }
    }
}

extern "C" void kernel_launch(void* const* d_in, const int* in_sizes, int n_in,
                              void* d_out, int out_size, void* d_ws, size_t ws_size,
                              hipStream_t stream) {
    const float* query = (const float*)d_in[0];
    const float* key_  = (const float*)d_in[1];
    const float* value = (const float*)d_in[2];
    const float* w_q = (const float*)d_in[3];
    const float* b_q = (const float*)d_in[4];
    const float* w_k = (const float*)d_in[5];
    const float* b_k = (const float*)d_in[6];
    const float* w_v = (const float*)d_in[7];
    const float* b_v = (const float*)d_in[8];
    const float* w_o = (const float*)d_in[9];
    const float* b_o = (const float*)d_in[10];
    float* out = (float*)d_out;

    char* ws = (char*)d_ws;
    bf16_t* Abuf = (bf16_t*)(ws);                       // 16MB (A staging, reused as ctx)
    bf16_t* qb   = (bf16_t*)(ws + (size_t)(16 << 20));  // 16MB
    bf16_t* kb   = (bf16_t*)(ws + (size_t)(32 << 20));  // 4MB
    bf16_t* vt   = (bf16_t*)(ws + (size_t)(36 << 20));  // 4MB (transposed V)
    bf16_t* wtq  = (bf16_t*)(ws + (size_t)(40 << 20));  // 8MB
    bf16_t* wtk  = (bf16_t*)(ws + (size_t)(48 << 20));  // 2MB
    bf16_t* wtv  = (bf16_t*)(ws + (size_t)(50 << 20));  // 2MB
    bf16_t* wto  = (bf16_t*)(ws + (size_t)(52 << 20));  // 8MB
    float* cosT  = (float*)(ws + (size_t)(60 << 20));   // 256KB
    float* sinT  = (float*)(ws + (size_t)(60 << 20) + (256 << 10));

    rope_table_kernel<<<S_LEN / 2, 64, 0, stream>>>(cosT, sinT);

    wt_conv_kernel<<<dim3(D_MODEL / 32, D_MODEL / 32), 256, 0, stream>>>(w_q, wtq, D_MODEL, D_MODEL);
    wt_conv_kernel<<<dim3(KV_D / 32, D_MODEL / 32), 256, 0, stream>>>(w_k, wtk, D_MODEL, KV_D);
    wt_conv_kernel<<<dim3(KV_D / 32, D_MODEL / 32), 256, 0, stream>>>(w_v, wtv, D_MODEL, KV_D);
    wt_conv_kernel<<<dim3(D_MODEL / 32, D_MODEL / 32), 256, 0, stream>>>(w_o, wto, D_MODEL, D_MODEL);

    const int n4blocks = (M_ROWS * D_MODEL / 4) / 256;

    // Q projection (+RoPE, pre-scaled by QK_SCALE): round-5 128x128 structure
    conv_bf16_kernel<<<n4blocks, 256, 0, stream>>>(query, Abuf);
    gqa_gemm_kernel<1, 0, 1><<<dim3(D_MODEL / 128, M_ROWS / 128), 256, 0, stream>>>(
        Abuf, wtq, b_q, qb, M_ROWS, D_MODEL, D_MODEL, cosT, sinT);

    // K + V projections fused (concurrent): fp32 A, RoPE->kb / transpose->vt
    gqa_kv_kernel<<<dim3(KV_D / 64, M_ROWS / 128, 2), 256, 0, stream>>>(
        key_, value, wtk, wtv, b_k, b_v, kb, vt, cosT, sinT);

    // Attention -> ctx (reuses Abuf); balanced pairing, 8-wave blocks
    gqa_attn_kernel<<<dim3(NQT / 2, N_QH, 2), 512, 0, stream>>>(qb, kb, vt, Abuf);

    // Output projection -> fp32 d_out
    gqa_gemm_kernel<0, 1, 0><<<dim3(D_MODEL / 128, M_ROWS / 128), 256, 0, stream>>>(
        Abuf, wto, b_o, out, M_ROWS, D_MODEL, D_MODEL, cosT, sinT);
}

// Round 9
// 268.952 us; speedup vs baseline: 1.2439x; 1.0659x over previous
//
#include <hip/hip_runtime.h>
#include <hip/hip_bf16.h>

typedef __hip_bfloat16 bf16_t;
typedef __attribute__((ext_vector_type(8))) short bf16x8;
typedef __attribute__((ext_vector_type(4))) float f32x4;

#define S_LEN   2048
#define D_MODEL 2048
#define N_QH    32
#define N_KVH   8
#define HEAD_D  64
#define KV_D    512
#define M_ROWS  4096
#define QK_SCALE (0.125f * 1.44269504088896340736f)   // att_scale * log2(e), folded into Q
#define NQT     16              // q-tiles of 128 rows

// ---------------- RoPE table (double precision, [2048][32] cos/sin) ----------------
__global__ void rope_table_kernel(float* __restrict__ cosT, float* __restrict__ sinT) {
    int pos = blockIdx.x * 2 + (threadIdx.x >> 5);
    int j   = threadIdx.x & 31;
    double invf = pow(10000.0, -(double)(2 * j) / 64.0);
    double a = (double)pos * invf;
    cosT[pos * 32 + j] = (float)cos(a);
    sinT[pos * 32 + j] = (float)sin(a);
}

// ---------------- weight transpose + convert: W[K][N] f32 -> Wt[N][K] bf16 ----------------
__global__ void wt_conv_kernel(const float* __restrict__ W, bf16_t* __restrict__ Wt,
                               int K, int N) {
    __shared__ float tile[32][33];
    int n0 = blockIdx.x * 32, k0 = blockIdx.y * 32;
    int tx = threadIdx.x & 31, ty = threadIdx.x >> 5;   // 32 x 8
#pragma unroll
    for (int i = 0; i < 4; i++) {
        int r = ty + i * 8;
        tile[r][tx] = W[(size_t)(k0 + r) * N + n0 + tx];
    }
    __syncthreads();
#pragma unroll
    for (int i = 0; i < 4; i++) {
        int r = ty + i * 8;
        Wt[(size_t)(n0 + r) * K + k0 + tx] = __float2bfloat16(tile[tx][r]);
    }
}

// ---------------- f32 -> bf16 elementwise (x4 vectorized) ----------------
struct __align__(8) bf16x4s { bf16_t x, y, z, w; };
__global__ void conv_bf16_kernel(const float* __restrict__ X, bf16_t* __restrict__ Y) {
    int i = blockIdx.x * 256 + threadIdx.x;
    float4 v = ((const float4*)X)[i];
    bf16x4s o;
    o.x = __float2bfloat16(v.x);
    o.y = __float2bfloat16(v.y);
    o.z = __float2bfloat16(v.z);
    o.w = __float2bfloat16(v.w);
    ((bf16x4s*)Y)[i] = o;
}

// ---------------- async 16B global->LDS ----------------
__device__ __forceinline__ void async_copy16(const bf16_t* g, bf16_t* l) {
    __builtin_amdgcn_global_load_lds((const __attribute__((address_space(1))) void*)g,
                                     (__attribute__((address_space(3))) void*)l, 16, 0, 0);
}

// ---------------- GEMM: C[M][N] = A[M][K] (bf16) * Bt[N][K]^T (bf16) + bias ----------------
// 128x128 tile, 2x2 wave grid, BK=64 (T2-swizzled LDS: pre-swizzled source chunk,
// XOR on fragment read; row&7 invariant under +32). Halves barrier count vs BK=32.
// ROPE: rotary epilogue (bf16 out); QSCALE: QK_SCALE fold; OUTF32: fp32 out.
template <int ROPE, int OUTF32, int QSCALE>
__global__ __launch_bounds__(256, 2)
void gqa_gemm_kernel(const bf16_t* __restrict__ A, const bf16_t* __restrict__ Bt,
                     const float* __restrict__ bias, void* __restrict__ Cout,
                     int M, int N, int K,
                     const float* __restrict__ cosT, const float* __restrict__ sinT) {
    __shared__ __align__(16) bf16_t As[128 * 64];
    __shared__ __align__(16) bf16_t Bs[128 * 64];

    const int t = threadIdx.x;
    const int am0 = blockIdx.y * 128;
    const int bn0 = blockIdx.x * 128;

    const int l = t & 63, w = t >> 6;
    const int wr = w >> 1, wc = w & 1;
    const int lr = l & 15, lk = l >> 4;

    f32x4 acc[4][4];
#pragma unroll
    for (int i = 0; i < 4; i++)
#pragma unroll
        for (int j = 0; j < 4; j++) acc[i][j] = (f32x4)0.0f;

    const int r0 = t >> 3;                  // 0..31
    const int c  = (t & 7) ^ (r0 & 7);      // pre-swizzled source chunk
    const bf16_t* aptr = A + (size_t)(am0 + r0) * K + c * 8;
    const bf16_t* bptr = Bt + (size_t)(bn0 + r0) * K + c * 8;
    bf16_t* aLds = As + r0 * 64 + (t & 7) * 8;
    bf16_t* bLds = Bs + r0 * 64 + (t & 7) * 8;

    for (int k0 = 0; k0 < K; k0 += 64) {
#pragma unroll
        for (int s = 0; s < 4; ++s) {
            async_copy16(aptr + (size_t)(s * 32) * K + k0, aLds + s * 2048);
            async_copy16(bptr + (size_t)(s * 32) * K + k0, bLds + s * 2048);
        }
        __syncthreads();

        bf16x8 af[4][2], bfr[4][2];
#pragma unroll
        for (int mi = 0; mi < 4; mi++)
#pragma unroll
            for (int ks = 0; ks < 2; ks++)
                af[mi][ks] = *(const bf16x8*)&As[(wr * 64 + mi * 16 + lr) * 64 +
                                 ((ks * 32 + lk * 8) ^ ((lr & 7) << 3))];
#pragma unroll
        for (int ni = 0; ni < 4; ni++)
#pragma unroll
            for (int ks = 0; ks < 2; ks++)
                bfr[ni][ks] = *(const bf16x8*)&Bs[(wc * 64 + ni * 16 + lr) * 64 +
                                  ((ks * 32 + lk * 8) ^ ((lr & 7) << 3))];
#pragma unroll
        for (int mi = 0; mi < 4; mi++)
#pragma unroll
            for (int ni = 0; ni < 4; ni++)
#pragma unroll
                for (int ks = 0; ks < 2; ks++)
                    acc[mi][ni] = __builtin_amdgcn_mfma_f32_16x16x32_bf16(
                        af[mi][ks], bfr[ni][ks], acc[mi][ni], 0, 0, 0);
        __syncthreads();
    }

    // Epilogue. C/D layout: col = lane&15, row = (lane>>4)*4 + reg
#pragma unroll
    for (int mi = 0; mi < 4; mi++) {
#pragma unroll
        for (int reg = 0; reg < 4; reg++) {
            int row = am0 + wr * 64 + mi * 16 + lk * 4 + reg;
            if (OUTF32) {
                float* out = (float*)Cout;
#pragma unroll
                for (int ni = 0; ni < 4; ni++) {
                    int col = bn0 + wc * 64 + ni * 16 + lr;
                    out[(size_t)row * N + col] = acc[mi][ni][reg] + bias[col];
                }
            } else if (ROPE) {
                bf16_t* out = (bf16_t*)Cout;
                int pos = row & (S_LEN - 1);
#pragma unroll
                for (int np = 0; np < 2; np++) {
                    int j = np * 16 + lr;              // d % 32 (head-local)
                    float cs = cosT[pos * 32 + j];
                    float sn = sinT[pos * 32 + j];
                    int col1 = bn0 + wc * 64 + np * 16 + lr;
                    float x1 = acc[mi][np][reg] + bias[col1];
                    float x2 = acc[mi][np + 2][reg] + bias[col1 + 32];
                    float o1 = x1 * cs - x2 * sn;
                    float o2 = x2 * cs + x1 * sn;
                    if (QSCALE) { o1 *= QK_SCALE; o2 *= QK_SCALE; }
                    out[(size_t)row * N + col1]      = __float2bfloat16(o1);
                    out[(size_t)row * N + col1 + 32] = __float2bfloat16(o2);
                }
            } else {
                bf16_t* out = (bf16_t*)Cout;
#pragma unroll
                for (int ni = 0; ni < 4; ni++) {
                    int col = bn0 + wc * 64 + ni * 16 + lr;
                    out[(size_t)row * N + col] =
                        __float2bfloat16(acc[mi][ni][reg] + bias[col]);
                }
            }
        }
    }
}

// ---------------- fused K+V projection kernel ----------------
// grid (KV_D/64, M/128, 2): z=0 -> K proj (+RoPE) into kb[M][512];
// z=1 -> V proj, TRANSPOSED into vt[(b*8+kvh)*64+d][s]. Both halves run
// concurrently. A read as fp32 directly (reg-staged + inline convert);
// B (bf16 weights) via global_load_lds. 128x64 tile, 4 waves stacked in M.
__global__ __launch_bounds__(256, 2)
void gqa_kv_kernel(const float* __restrict__ Key, const float* __restrict__ Val,
                   const bf16_t* __restrict__ Wtk, const bf16_t* __restrict__ Wtv,
                   const float* __restrict__ bk, const float* __restrict__ bv,
                   bf16_t* __restrict__ Kout, bf16_t* __restrict__ VtOut,
                   const float* __restrict__ cosT, const float* __restrict__ sinT) {
    constexpr int K = D_MODEL;
    __shared__ __align__(16) bf16_t As[128 * 32];
    __shared__ __align__(16) bf16_t Bs[64 * 32];
    __shared__ float VtE[4 * 64 * 33];                 // per-wave [64 d][32 s +1]

    const int z = blockIdx.z;
    const float* A32  = z ? Val : Key;
    const bf16_t* Bt  = z ? Wtv : Wtk;
    const float* bias = z ? bv : bk;

    const int t = threadIdx.x;
    const int am0 = blockIdx.y * 128;
    const int bn0 = blockIdx.x * 64;
    const int l = t & 63, w = t >> 6;
    const int lr = l & 15, lk = l >> 4;

    f32x4 acc[2][4];
#pragma unroll
    for (int i = 0; i < 2; i++)
#pragma unroll
        for (int j = 0; j < 4; j++) acc[i][j] = (f32x4)0.0f;

    const int srow = t >> 2;            // 0..63
    const int scol = (t & 3) * 8;
    const float*  aptr = A32 + (size_t)(am0 + srow) * K + scol;
    const bf16_t* bptr = Bt + (size_t)(bn0 + srow) * K + scol;
    bf16_t* bLds = Bs + t * 8;

    for (int k0 = 0; k0 < K; k0 += 32) {
        async_copy16(bptr + k0, bLds);          // B: async direct-to-LDS
#pragma unroll
        for (int rb = 0; rb < 2; ++rb) {        // A: fp32 -> bf16 reg-staged
            const float* ap = aptr + (size_t)(rb * 64) * K + k0;
            float4 v0 = ((const float4*)ap)[0];
            float4 v1 = ((const float4*)ap)[1];
            union { bf16x8 v; bf16_t e[8]; } u;
            u.e[0] = __float2bfloat16(v0.x); u.e[1] = __float2bfloat16(v0.y);
            u.e[2] = __float2bfloat16(v0.z); u.e[3] = __float2bfloat16(v0.w);
            u.e[4] = __float2bfloat16(v1.x); u.e[5] = __float2bfloat16(v1.y);
            u.e[6] = __float2bfloat16(v1.z); u.e[7] = __float2bfloat16(v1.w);
            *(bf16x8*)&As[rb * 2048 + t * 8] = u.v;
        }
        __syncthreads();

        bf16x8 af[2], bfr[4];
#pragma unroll
        for (int mi = 0; mi < 2; mi++)
            af[mi] = *(const bf16x8*)&As[(w * 32 + mi * 16 + lr) * 32 + lk * 8];
#pragma unroll
        for (int ni = 0; ni < 4; ni++)
            bfr[ni] = *(const bf16x8*)&Bs[(ni * 16 + lr) * 32 + lk * 8];
#pragma unroll
        for (int mi = 0; mi < 2; mi++)
#pragma unroll
            for (int ni = 0; ni < 4; ni++)
                acc[mi][ni] = __builtin_amdgcn_mfma_f32_16x16x32_bf16(af[mi], bfr[ni],
                                                                      acc[mi][ni], 0, 0, 0);
        __syncthreads();
    }

    if (z == 0) {
        // K projection: RoPE epilogue, row-major kb[M][KV_D]
#pragma unroll
        for (int mi = 0; mi < 2; mi++)
#pragma unroll
            for (int reg = 0; reg < 4; reg++) {
                int row = am0 + w * 32 + mi * 16 + lk * 4 + reg;
                int pos = row & (S_LEN - 1);
#pragma unroll
                for (int np = 0; np < 2; np++) {
                    int j = np * 16 + lr;
                    float cs = cosT[pos * 32 + j];
                    float sn = sinT[pos * 32 + j];
                    int col1 = bn0 + np * 16 + lr;
                    float x1 = acc[mi][np][reg] + bias[col1];
                    float x2 = acc[mi][np + 2][reg] + bias[col1 + 32];
                    Kout[(size_t)row * KV_D + col1]      = __float2bfloat16(x1 * cs - x2 * sn);
                    Kout[(size_t)row * KV_D + col1 + 32] = __float2bfloat16(x2 * cs + x1 * sn);
                }
            }
    } else {
        // V projection: transpose via per-wave LDS tile [64 d][32 s +1 pad]
#pragma unroll
        for (int mi = 0; mi < 2; mi++)
#pragma unroll
            for (int reg = 0; reg < 4; reg++)
#pragma unroll
                for (int ni = 0; ni < 4; ni++)
                    VtE[(w * 64 + ni * 16 + lr) * 33 + mi * 16 + lk * 4 + reg] =
                        acc[mi][ni][reg] + bias[bn0 + ni * 16 + lr];
        __syncthreads();
        const int d = l;                       // 0..63
        const int bI = am0 >> 11;
        const int kvhI = bn0 >> 6;
        const int sl = (am0 & (S_LEN - 1)) + w * 32;
        bf16_t* dst = VtOut + ((size_t)(bI * N_KVH + kvhI) * HEAD_D + d) * S_LEN + sl;
        const float* src = &VtE[(w * 64 + d) * 33];
#pragma unroll
        for (int c = 0; c < 4; c++) {
            union { bf16x8 v; bf16_t e[8]; } u;
#pragma unroll
            for (int j = 0; j < 8; j++) u.e[j] = __float2bfloat16(src[c * 8 + j]);
            *(bf16x8*)(dst + c * 8) = u.v;
        }
    }
}

// ---------------- staging (512 threads: one 16B async copy per thread) ----------------
// LDS linear [64 key][64 d]; element (key, e) holds global d-chunk (e/8)^(key&7).
__device__ __forceinline__ void stage_K8(const bf16_t* KB, bf16_t* dst, int kt, int t) {
    const int skey = t >> 3;                // 0..63
    const int c    = (t & 7) ^ (skey & 7);  // source chunk
    async_copy16(KB + (size_t)(kt * 64 + skey) * KV_D + c * 8, dst + t * 8);
}
// LDS linear [64 d][64 key]; element (d, e) holds global key-chunk (e/8)^(d&7).
__device__ __forceinline__ void stage_V8(const bf16_t* VTb, bf16_t* dst, int kt, int t) {
    const int sd = t >> 3;                  // 0..63
    const int c  = (t & 7) ^ (sd & 7);      // source chunk
    async_copy16(VTb + (size_t)sd * S_LEN + kt * 64 + c * 8, dst + t * 8);
}

// ---------------- causal GQA flash attention (swapped-QK^T, 8 waves) ----------------
// 1D grid of 512 blocks with XCD-aware decode: blocks sharing one (b,kvh) KV
// panel land on one XCD's L2 (2 combos x 2MB per XCD). Balanced pairing:
// block does q-tiles p and NQT-1-p. Swapped QK^T; defer-max (T13).
__global__ __launch_bounds__(512, 4)
void gqa_attn_kernel(const bf16_t* __restrict__ Q, const bf16_t* __restrict__ Kb,
                     const bf16_t* __restrict__ VT, bf16_t* __restrict__ Ctx) {
    __shared__ __align__(16) bf16_t Ks[2][64 * 64];    // [key][d], source-swizzled
    __shared__ __align__(16) bf16_t Vs[2][64 * 64];    // [d][key], source-swizzled
    __shared__ __align__(16) bf16_t Pw[8][16 * 72];    // per-wave P [q][key]

    const int t = threadIdx.x, l = t & 63, w = t >> 6;   // w = 0..7
    const int lr = l & 15, lk = l >> 4;

    // XCD-aware decode: xcd = flat&7 under round-robin dispatch.
    const int flat = blockIdx.x;
    const int xcd = flat & 7, j0 = flat >> 3;            // j0: 0..63
    const int combo  = xcd * 2 + (j0 >> 5);              // b*8+kvh (16 combos)
    const int within = j0 & 31;                          // 4 heads x 8 pairs
    const int b   = combo >> 3;
    const int kvh = combo & 7;
    const int h   = kvh * 4 + (within >> 3);
    const int p   = within & 7;

    const bf16_t* KB  = Kb + (size_t)b * S_LEN * KV_D + kvh * HEAD_D;
    const bf16_t* VTb = VT + ((size_t)(b * N_KVH + kvh) * HEAD_D) * S_LEN;

#pragma unroll
    for (int half = 0; half < 2; ++half) {
        const int qt  = half ? (NQT - 1 - p) : p;
        const int q0w = qt * 128 + w * 16;
        const int qg  = q0w + lr;                       // this lane's q row

        // Q fragments (A-layout: row=lane&15 -> q, k=(lane>>4)*8+i -> d)
        bf16x8 qf[2];
        {
            const bf16_t* qrow = Q + ((size_t)(b * S_LEN + qg)) * D_MODEL + h * HEAD_D;
            qf[0] = *(const bf16x8*)(qrow + lk * 8);
            qf[1] = *(const bf16x8*)(qrow + 32 + lk * 8);
        }

        float mrow = -1e30f, lrow = 0.f;
        f32x4 oaccT[4];                                 // O^T: d = df*16+lk*4+r, q = lr
#pragma unroll
        for (int df = 0; df < 4; df++) oaccT[df] = (f32x4)0.0f;

        const int nkt = 2 * qt + 2;

        stage_K8(KB, Ks[0], 0, t);
        stage_V8(VTb, Vs[0], 0, t);
        __syncthreads();

        int cur = 0;
        for (int kt = 0; kt < nkt; ++kt) {
            const bool pre = (kt + 1 < nkt);
            if (pre) {
                stage_K8(KB, Ks[cur ^ 1], kt + 1, t);
                stage_V8(VTb, Vs[cur ^ 1], kt + 1, t);
            }

            if (kt * 64 <= q0w + 15) {                  // wave-uniform causal skip
                const bool diag = (kt * 64 + 63 > q0w);

                // ---- S^T = mfma(K, Q): keys in rows, q in cols (pre-scaled) ----
                f32x4 sfrT[4];
#pragma unroll
                for (int ni = 0; ni < 4; ni++) sfrT[ni] = (f32x4)0.0f;
                __builtin_amdgcn_s_setprio(1);
#pragma unroll
                for (int ni = 0; ni < 4; ni++)
#pragma unroll
                    for (int ks = 0; ks < 2; ks++) {
                        bf16x8 kf = *(const bf16x8*)&Ks[cur][(ni * 16 + lr) * 64 +
                                        ((ks * 32 + lk * 8) ^ ((lr & 7) << 3))];
                        sfrT[ni] = __builtin_amdgcn_mfma_f32_16x16x32_bf16(kf, qf[ks],
                                                                           sfrT[ni], 0, 0, 0);
                    }
                __builtin_amdgcn_s_setprio(0);

                // ---- mask + in-register row max (already log2-scaled) ----
                float pv[16];
                float mx = -1e30f;
#pragma unroll
                for (int ni = 0; ni < 4; ni++)
#pragma unroll
                    for (int r = 0; r < 4; r++) {
                        float sc = sfrT[ni][r];
                        if (diag) {
                            int keyg = kt * 64 + ni * 16 + lk * 4 + r;
                            if (keyg > qg) sc = -1e30f;
                        }
                        pv[ni * 4 + r] = sc;
                        mx = fmaxf(mx, sc);
                    }
                mx = fmaxf(mx, __shfl_xor(mx, 16));
                mx = fmaxf(mx, __shfl_xor(mx, 32));

                // ---- defer-max: only rescale when some lane's max grew > 8 ----
                float mn = fmaxf(mrow, mx);
                if (!__all(mn - mrow <= 8.0f)) {
                    float csc = exp2f(mrow - mn);
                    lrow *= csc;
#pragma unroll
                    for (int df = 0; df < 4; df++) oaccT[df] *= csc;
                    mrow = mn;
                }

                float rsp[4] = {0.f, 0.f, 0.f, 0.f};
#pragma unroll
                for (int ni = 0; ni < 4; ni++)
#pragma unroll
                    for (int r = 0; r < 4; r++) {
                        float e = exp2f(pv[ni * 4 + r] - mrow);
                        pv[ni * 4 + r] = e;
                        rsp[ni] += e;
                    }
                float rs = (rsp[0] + rsp[1]) + (rsp[2] + rsp[3]);
                rs += __shfl_xor(rs, 16);
                rs += __shfl_xor(rs, 32);
                lrow += rs;

                // ---- P^T -> per-wave LDS as P[q][key]; 4 consecutive keys -> b64 ----
#pragma unroll
                for (int ni = 0; ni < 4; ni++) {
                    bf16x4s pk;
                    pk.x = __float2bfloat16(pv[ni * 4 + 0]);
                    pk.y = __float2bfloat16(pv[ni * 4 + 1]);
                    pk.z = __float2bfloat16(pv[ni * 4 + 2]);
                    pk.w = __float2bfloat16(pv[ni * 4 + 3]);
                    *(bf16x4s*)&Pw[w][lr * 72 + ni * 16 + lk * 4] = pk;
                }

                // ---- O^T += mfma(V^T, P^T) ----
                __builtin_amdgcn_s_setprio(1);
#pragma unroll
                for (int ks = 0; ks < 2; ks++) {
                    bf16x8 pf = *(const bf16x8*)&Pw[w][lr * 72 + ks * 32 + lk * 8];
#pragma unroll
                    for (int df = 0; df < 4; df++) {
                        bf16x8 vf = *(const bf16x8*)&Vs[cur][(df * 16 + lr) * 64 +
                                        ((ks * 32 + lk * 8) ^ ((lr & 7) << 3))];
                        oaccT[df] = __builtin_amdgcn_mfma_f32_16x16x32_bf16(vf, pf,
                                            oaccT[df], 0, 0, 0);
                    }
                }
                __builtin_amdgcn_s_setprio(0);
            }

            __syncthreads();
            cur ^= 1;
        }

        // ---- normalize + write ctx (lane owns q = qg; d = df*16+lk*4+0..3) ----
        {
            float inv = 1.0f / lrow;
            bf16_t* crow = Ctx + ((size_t)(b * S_LEN + qg)) * D_MODEL + h * HEAD_D;
#pragma unroll
            for (int df = 0; df < 4; df++) {
                bf16x4s ov;
                ov.x = __float2bfloat16(oaccT[df][0] * inv);
                ov.y = __float2bfloat16(oaccT[df][1] * inv);
                ov.z = __float2bfloat16(oaccT[df][2] * inv);
                ov.w = __float2bfloat16(oaccT[df][3] * inv);
                *(bf16x4s*)(crow + df * 16 + lk * 4) = ov;
            }
        }
    }
}

extern "C" void kernel_launch(void* const* d_in, const int* in_sizes, int n_in,
                              void* d_out, int out_size, void* d_ws, size_t ws_size,
                              hipStream_t stream) {
    const float* query = (const float*)d_in[0];
    const float* key_  = (const float*)d_in[1];
    const float* value = (const float*)d_in[2];
    const float* w_q = (const float*)d_in[3];
    const float* b_q = (const float*)d_in[4];
    const float* w_k = (const float*)d_in[5];
    const float* b_k = (const float*)d_in[6];
    const float* w_v = (const float*)d_in[7];
    const float* b_v = (const float*)d_in[8];
    const float* w_o = (const float*)d_in[9];
    const float* b_o = (const float*)d_in[10];
    float* out = (float*)d_out;

    char* ws = (char*)d_ws;
    bf16_t* Abuf = (bf16_t*)(ws);                       // 16MB (A staging, reused as ctx)
    bf16_t* qb   = (bf16_t*)(ws + (size_t)(16 << 20));  // 16MB
    bf16_t* kb   = (bf16_t*)(ws + (size_t)(32 << 20));  // 4MB
    bf16_t* vt   = (bf16_t*)(ws + (size_t)(36 << 20));  // 4MB (transposed V)
    bf16_t* wtq  = (bf16_t*)(ws + (size_t)(40 << 20));  // 8MB
    bf16_t* wtk  = (bf16_t*)(ws + (size_t)(48 << 20));  // 2MB
    bf16_t* wtv  = (bf16_t*)(ws + (size_t)(50 << 20));  // 2MB
    bf16_t* wto  = (bf16_t*)(ws + (size_t)(52 << 20));  // 8MB
    float* cosT  = (float*)(ws + (size_t)(60 << 20));   // 256KB
    float* sinT  = (float*)(ws + (size_t)(60 << 20) + (256 << 10));

    rope_table_kernel<<<S_LEN / 2, 64, 0, stream>>>(cosT, sinT);

    wt_conv_kernel<<<dim3(D_MODEL / 32, D_MODEL / 32), 256, 0, stream>>>(w_q, wtq, D_MODEL, D_MODEL);
    wt_conv_kernel<<<dim3(KV_D / 32, D_MODEL / 32), 256, 0, stream>>>(w_k, wtk, D_MODEL, KV_D);
    wt_conv_kernel<<<dim3(KV_D / 32, D_MODEL / 32), 256, 0, stream>>>(w_v, wtv, D_MODEL, KV_D);
    wt_conv_kernel<<<dim3(D_MODEL / 32, D_MODEL / 32), 256, 0, stream>>>(w_o, wto, D_MODEL, D_MODEL);

    const int n4blocks = (M_ROWS * D_MODEL / 4) / 256;

    // Q projection (+RoPE, pre-scaled by QK_SCALE)
    conv_bf16_kernel<<<n4blocks, 256, 0, stream>>>(query, Abuf);
    gqa_gemm_kernel<1, 0, 1><<<dim3(D_MODEL / 128, M_ROWS / 128), 256, 0, stream>>>(
        Abuf, wtq, b_q, qb, M_ROWS, D_MODEL, D_MODEL, cosT, sinT);

    // K + V projections fused (concurrent): fp32 A, RoPE->kb / transpose->vt
    gqa_kv_kernel<<<dim3(KV_D / 64, M_ROWS / 128, 2), 256, 0, stream>>>(
        key_, value, wtk, wtv, b_k, b_v, kb, vt, cosT, sinT);

    // Attention -> ctx (reuses Abuf); XCD-aware 1D grid, balanced pairing
    gqa_attn_kernel<<<512, 512, 0, stream>>>(qb, kb, vt, Abuf);

    // Output projection -> fp32 d_out
    gqa_gemm_kernel<0, 1, 0><<<dim3(D_MODEL / 128, M_ROWS / 128), 256, 0, stream>>>(
        Abuf, wto, b_o, out, M_ROWS, D_MODEL, D_MODEL, cosT, sinT);
}

// Round 10
// 266.314 us; speedup vs baseline: 1.2563x; 1.0099x over previous
//
#include <hip/hip_runtime.h>
#include <hip/hip_bf16.h>

typedef __hip_bfloat16 bf16_t;
typedef __attribute__((ext_vector_type(8))) short bf16x8;
typedef __attribute__((ext_vector_type(4))) float f32x4;

#define S_LEN   2048
#define D_MODEL 2048
#define N_QH    32
#define N_KVH   8
#define HEAD_D  64
#define KV_D    512
#define M_ROWS  4096
#define QK_SCALE (0.125f * 1.44269504088896340736f)   // att_scale * log2(e), folded into Q
#define NQT     16              // q-tiles of 128 rows

// ---------------- RoPE table (double precision, [2048][32] cos/sin) ----------------
__global__ void rope_table_kernel(float* __restrict__ cosT, float* __restrict__ sinT) {
    int pos = blockIdx.x * 2 + (threadIdx.x >> 5);
    int j   = threadIdx.x & 31;
    double invf = pow(10000.0, -(double)(2 * j) / 64.0);
    double a = (double)pos * invf;
    cosT[pos * 32 + j] = (float)cos(a);
    sinT[pos * 32 + j] = (float)sin(a);
}

// ---------------- all 4 weight transposes in one dispatch ----------------
// grid (160, 64): x -> {wq:0..63, wk:64..79, wv:80..95, wo:96..159}, y -> k-tile.
__global__ void wt_conv_all_kernel(const float* __restrict__ wq, const float* __restrict__ wk,
                                   const float* __restrict__ wv, const float* __restrict__ wo,
                                   bf16_t* __restrict__ tq, bf16_t* __restrict__ tk,
                                   bf16_t* __restrict__ tv, bf16_t* __restrict__ to) {
    __shared__ float tile[32][33];
    const int x = blockIdx.x;
    const float* W; bf16_t* Wt; int N, nb;
    if (x < 64)       { W = wq; Wt = tq; N = D_MODEL; nb = x; }
    else if (x < 80)  { W = wk; Wt = tk; N = KV_D;    nb = x - 64; }
    else if (x < 96)  { W = wv; Wt = tv; N = KV_D;    nb = x - 80; }
    else              { W = wo; Wt = to; N = D_MODEL; nb = x - 96; }
    const int K = D_MODEL;
    int n0 = nb * 32, k0 = blockIdx.y * 32;
    int tx = threadIdx.x & 31, ty = threadIdx.x >> 5;   // 32 x 8
#pragma unroll
    for (int i = 0; i < 4; i++) {
        int r = ty + i * 8;
        tile[r][tx] = W[(size_t)(k0 + r) * N + n0 + tx];
    }
    __syncthreads();
#pragma unroll
    for (int i = 0; i < 4; i++) {
        int r = ty + i * 8;
        Wt[(size_t)(n0 + r) * K + k0 + tx] = __float2bfloat16(tile[tx][r]);
    }
}

struct __align__(8) bf16x4s { bf16_t x, y, z, w; };

// ---------------- async 16B global->LDS ----------------
__device__ __forceinline__ void async_copy16(const bf16_t* g, bf16_t* l) {
    __builtin_amdgcn_global_load_lds((const __attribute__((address_space(1))) void*)g,
                                     (__attribute__((address_space(3))) void*)l, 16, 0, 0);
}

// ---------------- GEMM: C[M][N] = A[M][K] (bf16) * Bt[N][K]^T (bf16) + bias ----------------
// 128x128 tile, 2x2 wave grid, BK=64 (T2-swizzled LDS: pre-swizzled source chunk,
// XOR on fragment read). ROPE: rotary epilogue; QSCALE: QK_SCALE fold; OUTF32: fp32 out.
template <int ROPE, int OUTF32, int QSCALE>
__global__ __launch_bounds__(256, 2)
void gqa_gemm_kernel(const bf16_t* __restrict__ A, const bf16_t* __restrict__ Bt,
                     const float* __restrict__ bias, void* __restrict__ Cout,
                     int M, int N, int K,
                     const float* __restrict__ cosT, const float* __restrict__ sinT) {
    __shared__ __align__(16) bf16_t As[128 * 64];
    __shared__ __align__(16) bf16_t Bs[128 * 64];

    const int t = threadIdx.x;
    const int am0 = blockIdx.y * 128;
    const int bn0 = blockIdx.x * 128;

    const int l = t & 63, w = t >> 6;
    const int wr = w >> 1, wc = w & 1;
    const int lr = l & 15, lk = l >> 4;

    f32x4 acc[4][4];
#pragma unroll
    for (int i = 0; i < 4; i++)
#pragma unroll
        for (int j = 0; j < 4; j++) acc[i][j] = (f32x4)0.0f;

    const int r0 = t >> 3;                  // 0..31
    const int c  = (t & 7) ^ (r0 & 7);      // pre-swizzled source chunk
    const bf16_t* aptr = A + (size_t)(am0 + r0) * K + c * 8;
    const bf16_t* bptr = Bt + (size_t)(bn0 + r0) * K + c * 8;
    bf16_t* aLds = As + r0 * 64 + (t & 7) * 8;
    bf16_t* bLds = Bs + r0 * 64 + (t & 7) * 8;

    for (int k0 = 0; k0 < K; k0 += 64) {
#pragma unroll
        for (int s = 0; s < 4; ++s) {
            async_copy16(aptr + (size_t)(s * 32) * K + k0, aLds + s * 2048);
            async_copy16(bptr + (size_t)(s * 32) * K + k0, bLds + s * 2048);
        }
        __syncthreads();

        bf16x8 af[4][2], bfr[4][2];
#pragma unroll
        for (int mi = 0; mi < 4; mi++)
#pragma unroll
            for (int ks = 0; ks < 2; ks++)
                af[mi][ks] = *(const bf16x8*)&As[(wr * 64 + mi * 16 + lr) * 64 +
                                 ((ks * 32 + lk * 8) ^ ((lr & 7) << 3))];
#pragma unroll
        for (int ni = 0; ni < 4; ni++)
#pragma unroll
            for (int ks = 0; ks < 2; ks++)
                bfr[ni][ks] = *(const bf16x8*)&Bs[(wc * 64 + ni * 16 + lr) * 64 +
                                  ((ks * 32 + lk * 8) ^ ((lr & 7) << 3))];
#pragma unroll
        for (int mi = 0; mi < 4; mi++)
#pragma unroll
            for (int ni = 0; ni < 4; ni++)
#pragma unroll
                for (int ks = 0; ks < 2; ks++)
                    acc[mi][ni] = __builtin_amdgcn_mfma_f32_16x16x32_bf16(
                        af[mi][ks], bfr[ni][ks], acc[mi][ni], 0, 0, 0);
        __syncthreads();
    }

    // Epilogue. C/D layout: col = lane&15, row = (lane>>4)*4 + reg
#pragma unroll
    for (int mi = 0; mi < 4; mi++) {
#pragma unroll
        for (int reg = 0; reg < 4; reg++) {
            int row = am0 + wr * 64 + mi * 16 + lk * 4 + reg;
            if (OUTF32) {
                float* out = (float*)Cout;
#pragma unroll
                for (int ni = 0; ni < 4; ni++) {
                    int col = bn0 + wc * 64 + ni * 16 + lr;
                    out[(size_t)row * N + col] = acc[mi][ni][reg] + bias[col];
                }
            } else if (ROPE) {
                bf16_t* out = (bf16_t*)Cout;
                int pos = row & (S_LEN - 1);
#pragma unroll
                for (int np = 0; np < 2; np++) {
                    int j = np * 16 + lr;              // d % 32 (head-local)
                    float cs = cosT[pos * 32 + j];
                    float sn = sinT[pos * 32 + j];
                    int col1 = bn0 + wc * 64 + np * 16 + lr;
                    float x1 = acc[mi][np][reg] + bias[col1];
                    float x2 = acc[mi][np + 2][reg] + bias[col1 + 32];
                    float o1 = x1 * cs - x2 * sn;
                    float o2 = x2 * cs + x1 * sn;
                    if (QSCALE) { o1 *= QK_SCALE; o2 *= QK_SCALE; }
                    out[(size_t)row * N + col1]      = __float2bfloat16(o1);
                    out[(size_t)row * N + col1 + 32] = __float2bfloat16(o2);
                }
            } else {
                bf16_t* out = (bf16_t*)Cout;
#pragma unroll
                for (int ni = 0; ni < 4; ni++) {
                    int col = bn0 + wc * 64 + ni * 16 + lr;
                    out[(size_t)row * N + col] =
                        __float2bfloat16(acc[mi][ni][reg] + bias[col]);
                }
            }
        }
    }
}

// ---------------- fused K+V projection + query-conv kernel ----------------
// grid 1024 x 256thr: blocks 0..255 -> K proj (+RoPE) -> kb; 256..511 -> V proj
// transposed -> vt; 512..1023 -> grid-stride query fp32->bf16 (overlaps KV).
// VtE (f32 [4][64][33]) unioned over dead As/Bs -> LDS 33792 B.
__global__ __launch_bounds__(256, 2)
void gqa_kvc_kernel(const float* __restrict__ Key, const float* __restrict__ Val,
                    const float* __restrict__ Query,
                    const bf16_t* __restrict__ Wtk, const bf16_t* __restrict__ Wtv,
                    const float* __restrict__ bk, const float* __restrict__ bv,
                    bf16_t* __restrict__ Kout, bf16_t* __restrict__ VtOut,
                    bf16_t* __restrict__ Qbf,
                    const float* __restrict__ cosT, const float* __restrict__ sinT) {
    __shared__ __align__(16) char smem[33792];
    bf16_t* As = (bf16_t*)smem;                    // [128*32] = 8192 B
    bf16_t* Bs = (bf16_t*)(smem + 8192);           // [64*32]  = 4096 B
    float*  VtE = (float*)smem;                    // [4*64*33] = 33792 B (post-loop)

    const int bx = blockIdx.x;
    const int t = threadIdx.x;

    if (bx >= 512) {
        // ---- query fp32 -> bf16, grid-stride ----
        int tid = (bx - 512) * 256 + t;
        const int total = M_ROWS * D_MODEL / 4;
#pragma unroll 4
        for (int i = tid; i < total; i += 512 * 256) {
            float4 v = ((const float4*)Query)[i];
            bf16x4s o;
            o.x = __float2bfloat16(v.x);
            o.y = __float2bfloat16(v.y);
            o.z = __float2bfloat16(v.z);
            o.w = __float2bfloat16(v.w);
            ((bf16x4s*)Qbf)[i] = o;
        }
        return;
    }

    constexpr int K = D_MODEL;
    const int z = bx >> 8;                 // 0: K proj, 1: V proj
    const int idx = bx & 255;
    const int bn0 = (idx & 7) * 64;
    const int am0 = (idx >> 3) * 128;

    const float* A32  = z ? Val : Key;
    const bf16_t* Bt  = z ? Wtv : Wtk;
    const float* bias = z ? bv : bk;

    const int l = t & 63, w = t >> 6;
    const int lr = l & 15, lk = l >> 4;

    f32x4 acc[2][4];
#pragma unroll
    for (int i = 0; i < 2; i++)
#pragma unroll
        for (int j = 0; j < 4; j++) acc[i][j] = (f32x4)0.0f;

    const int srow = t >> 2;            // 0..63
    const int scol = (t & 3) * 8;
    const float*  aptr = A32 + (size_t)(am0 + srow) * K + scol;
    const bf16_t* bptr = Bt + (size_t)(bn0 + srow) * K + scol;
    bf16_t* bLds = Bs + t * 8;

    for (int k0 = 0; k0 < K; k0 += 32) {
        async_copy16(bptr + k0, bLds);          // B: async direct-to-LDS
#pragma unroll
        for (int rb = 0; rb < 2; ++rb) {        // A: fp32 -> bf16 reg-staged
            const float* ap = aptr + (size_t)(rb * 64) * K + k0;
            float4 v0 = ((const float4*)ap)[0];
            float4 v1 = ((const float4*)ap)[1];
            union { bf16x8 v; bf16_t e[8]; } u;
            u.e[0] = __float2bfloat16(v0.x); u.e[1] = __float2bfloat16(v0.y);
            u.e[2] = __float2bfloat16(v0.z); u.e[3] = __float2bfloat16(v0.w);
            u.e[4] = __float2bfloat16(v1.x); u.e[5] = __float2bfloat16(v1.y);
            u.e[6] = __float2bfloat16(v1.z); u.e[7] = __float2bfloat16(v1.w);
            *(bf16x8*)&As[rb * 2048 + t * 8] = u.v;
        }
        __syncthreads();

        bf16x8 af[2], bfr[4];
#pragma unroll
        for (int mi = 0; mi < 2; mi++)
            af[mi] = *(const bf16x8*)&As[(w * 32 + mi * 16 + lr) * 32 + lk * 8];
#pragma unroll
        for (int ni = 0; ni < 4; ni++)
            bfr[ni] = *(const bf16x8*)&Bs[(ni * 16 + lr) * 32 + lk * 8];
#pragma unroll
        for (int mi = 0; mi < 2; mi++)
#pragma unroll
            for (int ni = 0; ni < 4; ni++)
                acc[mi][ni] = __builtin_amdgcn_mfma_f32_16x16x32_bf16(af[mi], bfr[ni],
                                                                      acc[mi][ni], 0, 0, 0);
        __syncthreads();
    }

    if (z == 0) {
        // K projection: RoPE epilogue, row-major kb[M][KV_D]
#pragma unroll
        for (int mi = 0; mi < 2; mi++)
#pragma unroll
            for (int reg = 0; reg < 4; reg++) {
                int row = am0 + w * 32 + mi * 16 + lk * 4 + reg;
                int pos = row & (S_LEN - 1);
#pragma unroll
                for (int np = 0; np < 2; np++) {
                    int j = np * 16 + lr;
                    float cs = cosT[pos * 32 + j];
                    float sn = sinT[pos * 32 + j];
                    int col1 = bn0 + np * 16 + lr;
                    float x1 = acc[mi][np][reg] + bias[col1];
                    float x2 = acc[mi][np + 2][reg] + bias[col1 + 32];
                    Kout[(size_t)row * KV_D + col1]      = __float2bfloat16(x1 * cs - x2 * sn);
                    Kout[(size_t)row * KV_D + col1 + 32] = __float2bfloat16(x2 * cs + x1 * sn);
                }
            }
    } else {
        // V projection: transpose via per-wave LDS tile [64 d][32 s +1 pad] (f32, unioned)
#pragma unroll
        for (int mi = 0; mi < 2; mi++)
#pragma unroll
            for (int reg = 0; reg < 4; reg++)
#pragma unroll
                for (int ni = 0; ni < 4; ni++)
                    VtE[(w * 64 + ni * 16 + lr) * 33 + mi * 16 + lk * 4 + reg] =
                        acc[mi][ni][reg] + bias[bn0 + ni * 16 + lr];
        __syncthreads();
        const int d = l;                       // 0..63
        const int bI = am0 >> 11;
        const int kvhI = bn0 >> 6;
        const int sl = (am0 & (S_LEN - 1)) + w * 32;
        bf16_t* dst = VtOut + ((size_t)(bI * N_KVH + kvhI) * HEAD_D + d) * S_LEN + sl;
        const float* src = &VtE[(w * 64 + d) * 33];
#pragma unroll
        for (int cc = 0; cc < 4; cc++) {
            union { bf16x8 v; bf16_t e[8]; } u;
#pragma unroll
            for (int j = 0; j < 8; j++) u.e[j] = __float2bfloat16(src[cc * 8 + j]);
            *(bf16x8*)(dst + cc * 8) = u.v;
        }
    }
}

// ---------------- staging (256 threads: two 16B async copies per thread) ----------------
// LDS linear [64 key][64 d]; element (key, e) holds global d-chunk (e/8)^(key&7).
__device__ __forceinline__ void stage_K4(const bf16_t* KB, bf16_t* dst, int kt, int t) {
    const int skey = t >> 3;                // 0..31
    const int c    = (t & 7) ^ (skey & 7);  // source chunk ((32+skey)&7 == skey&7)
#pragma unroll
    for (int s = 0; s < 2; ++s)
        async_copy16(KB + (size_t)(kt * 64 + s * 32 + skey) * KV_D + c * 8,
                     dst + s * 2048 + t * 8);
}
// LDS linear [64 d][64 key]; element (d, e) holds global key-chunk (e/8)^(d&7).
__device__ __forceinline__ void stage_V4(const bf16_t* VTb, bf16_t* dst, int kt, int t) {
    const int sd = t >> 3;                  // 0..31
    const int c  = (t & 7) ^ (sd & 7);      // source chunk
#pragma unroll
    for (int s = 0; s < 2; ++s)
        async_copy16(VTb + (size_t)(s * 32 + sd) * S_LEN + kt * 64 + c * 8,
                     dst + s * 2048 + t * 8);
}

// ---------------- causal GQA flash attention (swapped-QK^T, 4 waves, 4 blocks/CU) ----------------
// 1024 blocks x 256 thr; LDS = 40960 B exactly -> 4 blocks/CU, 16 waves/CU.
// Block = (b, kvh, h, pair p, sub-half): 64 q-rows of paired tiles p and 15-p.
// XCD decode keeps each (b,kvh) KV panel on one XCD's L2. Pw stride-64 XOR-swizzled.
__global__ __launch_bounds__(256, 4)
void gqa_attn_kernel(const bf16_t* __restrict__ Q, const bf16_t* __restrict__ Kb,
                     const bf16_t* __restrict__ VT, bf16_t* __restrict__ Ctx) {
    __shared__ __align__(16) bf16_t Ks[2][64 * 64];    // 16384 B
    __shared__ __align__(16) bf16_t Vs[2][64 * 64];    // 16384 B
    __shared__ __align__(16) bf16_t Pw[4][16 * 64];    //  8192 B (XOR-swizzled)

    const int t = threadIdx.x, l = t & 63, w = t >> 6;   // w = 0..3
    const int lr = l & 15, lk = l >> 4;

    // XCD-aware decode: xcd = flat&7 under round-robin dispatch.
    const int flat = blockIdx.x;
    const int xcd = flat & 7, j0 = flat >> 3;            // j0: 0..127
    const int combo  = xcd * 2 + (j0 >> 6);              // b*8+kvh (16 combos)
    const int within = j0 & 63;                          // 4 heads x 8 pairs x 2 subs
    const int b   = combo >> 3;
    const int kvh = combo & 7;
    const int h   = kvh * 4 + (within >> 4);
    const int rem = within & 15;
    const int p   = rem >> 1;
    const int sub = rem & 1;

    const bf16_t* KB  = Kb + (size_t)b * S_LEN * KV_D + kvh * HEAD_D;
    const bf16_t* VTb = VT + ((size_t)(b * N_KVH + kvh) * HEAD_D) * S_LEN;

#pragma unroll
    for (int half = 0; half < 2; ++half) {
        const int qt  = half ? (NQT - 1 - p) : p;
        const int q0w = qt * 128 + sub * 64 + w * 16;
        const int qg  = q0w + lr;                       // this lane's q row

        // Q fragments (A-layout: row=lane&15 -> q, k=(lane>>4)*8+i -> d)
        bf16x8 qf[2];
        {
            const bf16_t* qrow = Q + ((size_t)(b * S_LEN + qg)) * D_MODEL + h * HEAD_D;
            qf[0] = *(const bf16x8*)(qrow + lk * 8);
            qf[1] = *(const bf16x8*)(qrow + 32 + lk * 8);
        }

        float mrow = -1e30f, lrow = 0.f;
        f32x4 oaccT[4];                                 // O^T: d = df*16+lk*4+r, q = lr
#pragma unroll
        for (int df = 0; df < 4; df++) oaccT[df] = (f32x4)0.0f;

        const int nkt = 2 * qt + sub + 1;               // tiles needed by this sub-half

        stage_K4(KB, Ks[0], 0, t);
        stage_V4(VTb, Vs[0], 0, t);
        __syncthreads();

        int cur = 0;
        for (int kt = 0; kt < nkt; ++kt) {
            const bool pre = (kt + 1 < nkt);
            if (pre) {
                stage_K4(KB, Ks[cur ^ 1], kt + 1, t);
                stage_V4(VTb, Vs[cur ^ 1], kt + 1, t);
            }

            if (kt * 64 <= q0w + 15) {                  // wave-uniform causal skip
                const bool diag = (kt * 64 + 63 > q0w);

                // ---- S^T = mfma(K, Q): keys in rows, q in cols (pre-scaled) ----
                f32x4 sfrT[4];
#pragma unroll
                for (int ni = 0; ni < 4; ni++) sfrT[ni] = (f32x4)0.0f;
                __builtin_amdgcn_s_setprio(1);
#pragma unroll
                for (int ni = 0; ni < 4; ni++)
#pragma unroll
                    for (int ks = 0; ks < 2; ks++) {
                        bf16x8 kf = *(const bf16x8*)&Ks[cur][(ni * 16 + lr) * 64 +
                                        ((ks * 32 + lk * 8) ^ ((lr & 7) << 3))];
                        sfrT[ni] = __builtin_amdgcn_mfma_f32_16x16x32_bf16(kf, qf[ks],
                                                                           sfrT[ni], 0, 0, 0);
                    }
                __builtin_amdgcn_s_setprio(0);

                // ---- mask + in-register row max (already log2-scaled) ----
                float pv[16];
                float mx = -1e30f;
#pragma unroll
                for (int ni = 0; ni < 4; ni++)
#pragma unroll
                    for (int r = 0; r < 4; r++) {
                        float sc = sfrT[ni][r];
                        if (diag) {
                            int keyg = kt * 64 + ni * 16 + lk * 4 + r;
                            if (keyg > qg) sc = -1e30f;
                        }
                        pv[ni * 4 + r] = sc;
                        mx = fmaxf(mx, sc);
                    }
                mx = fmaxf(mx, __shfl_xor(mx, 16));
                mx = fmaxf(mx, __shfl_xor(mx, 32));

                // ---- defer-max: only rescale when some lane's max grew > 8 ----
                float mn = fmaxf(mrow, mx);
                if (!__all(mn - mrow <= 8.0f)) {
                    float csc = exp2f(mrow - mn);
                    lrow *= csc;
#pragma unroll
                    for (int df = 0; df < 4; df++) oaccT[df] *= csc;
                    mrow = mn;
                }

                float rsp[4] = {0.f, 0.f, 0.f, 0.f};
#pragma unroll
                for (int ni = 0; ni < 4; ni++)
#pragma unroll
                    for (int r = 0; r < 4; r++) {
                        float e = exp2f(pv[ni * 4 + r] - mrow);
                        pv[ni * 4 + r] = e;
                        rsp[ni] += e;
                    }
                float rs = (rsp[0] + rsp[1]) + (rsp[2] + rsp[3]);
                rs += __shfl_xor(rs, 16);
                rs += __shfl_xor(rs, 32);
                lrow += rs;

                // ---- P^T -> per-wave LDS P[q][key], stride 64, XOR-swizzled ----
#pragma unroll
                for (int ni = 0; ni < 4; ni++) {
                    bf16x4s pk;
                    pk.x = __float2bfloat16(pv[ni * 4 + 0]);
                    pk.y = __float2bfloat16(pv[ni * 4 + 1]);
                    pk.z = __float2bfloat16(pv[ni * 4 + 2]);
                    pk.w = __float2bfloat16(pv[ni * 4 + 3]);
                    *(bf16x4s*)&Pw[w][lr * 64 + ((ni * 16 + lk * 4) ^ ((lr & 7) << 3))] = pk;
                }

                // ---- O^T += mfma(V^T, P^T) ----
                __builtin_amdgcn_s_setprio(1);
#pragma unroll
                for (int ks = 0; ks < 2; ks++) {
                    bf16x8 pf = *(const bf16x8*)&Pw[w][lr * 64 +
                                    ((ks * 32 + lk * 8) ^ ((lr & 7) << 3))];
#pragma unroll
                    for (int df = 0; df < 4; df++) {
                        bf16x8 vf = *(const bf16x8*)&Vs[cur][(df * 16 + lr) * 64 +
                                        ((ks * 32 + lk * 8) ^ ((lr & 7) << 3))];
                        oaccT[df] = __builtin_amdgcn_mfma_f32_16x16x32_bf16(vf, pf,
                                            oaccT[df], 0, 0, 0);
                    }
                }
                __builtin_amdgcn_s_setprio(0);
            }

            __syncthreads();
            cur ^= 1;
        }

        // ---- normalize + write ctx (lane owns q = qg; d = df*16+lk*4+0..3) ----
        {
            float inv = 1.0f / lrow;
            bf16_t* crow = Ctx + ((size_t)(b * S_LEN + qg)) * D_MODEL + h * HEAD_D;
#pragma unroll
            for (int df = 0; df < 4; df++) {
                bf16x4s ov;
                ov.x = __float2bfloat16(oaccT[df][0] * inv);
                ov.y = __float2bfloat16(oaccT[df][1] * inv);
                ov.z = __float2bfloat16(oaccT[df][2] * inv);
                ov.w = __float2bfloat16(oaccT[df][3] * inv);
                *(bf16x4s*)(crow + df * 16 + lk * 4) = ov;
            }
        }
    }
}

extern "C" void kernel_launch(void* const* d_in, const int* in_sizes, int n_in,
                              void* d_out, int out_size, void* d_ws, size_t ws_size,
                              hipStream_t stream) {
    const float* query = (const float*)d_in[0];
    const float* key_  = (const float*)d_in[1];
    const float* value = (const float*)d_in[2];
    const float* w_q = (const float*)d_in[3];
    const float* b_q = (const float*)d_in[4];
    const float* w_k = (const float*)d_in[5];
    const float* b_k = (const float*)d_in[6];
    const float* w_v = (const float*)d_in[7];
    const float* b_v = (const float*)d_in[8];
    const float* w_o = (const float*)d_in[9];
    const float* b_o = (const float*)d_in[10];
    float* out = (float*)d_out;

    char* ws = (char*)d_ws;
    bf16_t* Abuf = (bf16_t*)(ws);                       // 16MB (Q bf16, reused as ctx)
    bf16_t* qb   = (bf16_t*)(ws + (size_t)(16 << 20));  // 16MB
    bf16_t* kb   = (bf16_t*)(ws + (size_t)(32 << 20));  // 4MB
    bf16_t* vt   = (bf16_t*)(ws + (size_t)(36 << 20));  // 4MB (transposed V)
    bf16_t* wtq  = (bf16_t*)(ws + (size_t)(40 << 20));  // 8MB
    bf16_t* wtk  = (bf16_t*)(ws + (size_t)(48 << 20));  // 2MB
    bf16_t* wtv  = (bf16_t*)(ws + (size_t)(50 << 20));  // 2MB
    bf16_t* wto  = (bf16_t*)(ws + (size_t)(52 << 20));  // 8MB
    float* cosT  = (float*)(ws + (size_t)(60 << 20));   // 256KB
    float* sinT  = (float*)(ws + (size_t)(60 << 20) + (256 << 10));

    rope_table_kernel<<<S_LEN / 2, 64, 0, stream>>>(cosT, sinT);

    // all 4 weight transposes in one dispatch
    wt_conv_all_kernel<<<dim3(160, 64), 256, 0, stream>>>(w_q, w_k, w_v, w_o,
                                                          wtq, wtk, wtv, wto);

    // K + V projections + query conv, one dispatch (KV overlaps conv)
    gqa_kvc_kernel<<<1024, 256, 0, stream>>>(key_, value, query, wtk, wtv,
                                             b_k, b_v, kb, vt, Abuf, cosT, sinT);

    // Q projection (+RoPE, pre-scaled by QK_SCALE)
    gqa_gemm_kernel<1, 0, 1><<<dim3(D_MODEL / 128, M_ROWS / 128), 256, 0, stream>>>(
        Abuf, wtq, b_q, qb, M_ROWS, D_MODEL, D_MODEL, cosT, sinT);

    // Attention -> ctx (reuses Abuf); 1024 blocks, 4 waves, 4 blocks/CU
    gqa_attn_kernel<<<1024, 256, 0, stream>>>(qb, kb, vt, Abuf);

    // Output projection -> fp32 d_out
    gqa_gemm_kernel<0, 1, 0><<<dim3(D_MODEL / 128, M_ROWS / 128), 256, 0, stream>>>(
        Abuf, wto, b_o, out, M_ROWS, D_MODEL, D_MODEL, cosT, sinT);
}